// Round 2
// baseline (441.870 us; speedup 1.0000x reference)
//
#include <hip/hip_runtime.h>
#include <hip/hip_bf16.h>

#define F1 128
#define F2 256
#define F3 128
#define CAP 64

// bucket geometry: 256 nodes per bucket
#define NB1D 391   // ceil(100000/256) dst1 buckets
#define NB2D 196   // ceil(50000/256)  dst2 buckets
#define NB1S 782   // ceil(200000/256) src1 buckets
#define NB2S 391   // ceil(100000/256) src2 buckets
#define CAPD 4608  // dst-bucket capacity (mean ~4092, sd ~64 -> 8 sigma)
#define CAPS 2432  // src-bucket capacity (mean ~2046, sd ~45 -> 8.5 sigma)
// gcnt layout offsets
#define GD1 0
#define GD2 391
#define GS1 587
#define GS2 1369

typedef __attribute__((ext_vector_type(8))) short bf16x8;
typedef __attribute__((ext_vector_type(4))) float f32x4;
typedef __attribute__((ext_vector_type(4))) unsigned int u32x4;

__device__ inline float bf2f(unsigned short u) {
    return __uint_as_float(((unsigned int)u) << 16);
}
__device__ inline unsigned short f2bf(float f) {
    __hip_bfloat16 b = __float2bfloat16(f);
    return *reinterpret_cast<unsigned short*>(&b);
}
__device__ inline unsigned int pack2(float lo, float hi) {
    return ((unsigned int)f2bf(hi) << 16) | f2bf(lo);
}

// ---------------------------------------------------------------- kernel A (1024 thr)
// block ranges: [0,A1) L1 edge scatter (8192 edges, 8 iters), [A1,A1+A2) L2,
// [+B3) x fp32->bf16 (8192 elems/block), [+64) weight permutes (32 blocks each).
__global__ __launch_bounds__(1024) void scatter_build(
    const int* __restrict__ src1, const int* __restrict__ dst1,
    const int* __restrict__ src2, const int* __restrict__ dst2,
    const float* __restrict__ x, const float* __restrict__ W1,
    const float* __restrict__ W2, int* __restrict__ gcnt,
    unsigned int* __restrict__ bkt_d1, unsigned int* __restrict__ bkt_d2,
    unsigned char* __restrict__ bkt_s1, unsigned char* __restrict__ bkt_s2,
    unsigned int* __restrict__ xn, unsigned short* __restrict__ Bp1,
    unsigned short* __restrict__ Bp2, int E1, int E2, int A1, int A2, int B3) {
    __shared__ int hist[1184];  // >= NB1D + NB1S = 1173
    int b = blockIdx.x, t = threadIdx.x;

    if (b < A1 + A2) {
        const int L1 = (b < A1);
        const int* __restrict__ src = L1 ? src1 : src2;
        const int* __restrict__ dst = L1 ? dst1 : dst2;
        const int E = L1 ? E1 : E2;
        const int NBd = L1 ? NB1D : NB2D;
        const int NBs = L1 ? NB1S : NB2S;
        int* gd = gcnt + (L1 ? GD1 : GD2);
        int* gs = gcnt + (L1 ? GS1 : GS2);
        unsigned int* bd = L1 ? bkt_d1 : bkt_d2;
        unsigned char* bs = L1 ? bkt_s1 : bkt_s2;
        int* hd = hist;
        int* hs = hist + NBd;
        for (int i = t; i < NBd + NBs; i += 1024) hist[i] = 0;
        __syncthreads();
        int e0 = (L1 ? b : b - A1) * 8192;
        // pass 1: local histograms; cache edges in registers for pass 2
        int se[8], de[8];
#pragma unroll
        for (int i = 0; i < 8; ++i) {
            int e = e0 + i * 1024 + t;
            se[i] = -1;
            de[i] = -1;
            if (e < E) {
                int s = src[e], d = dst[e];
                se[i] = s;
                de[i] = d;
                atomicAdd(&hd[d >> 8], 1);
                atomicAdd(&hs[s >> 8], 1);
            }
        }
        __syncthreads();
        // reserve global space; hist becomes cursor (global base)
        for (int i = t; i < NBd; i += 1024) {
            int c = hd[i];
            hd[i] = c ? atomicAdd(&gd[i], c) : 0;
        }
        for (int i = t; i < NBs; i += 1024) {
            int c = hs[i];
            hs[i] = c ? atomicAdd(&gs[i], c) : 0;
        }
        __syncthreads();
        // pass 2: scatter into buckets (runs contiguous per (block,bucket))
#pragma unroll
        for (int i = 0; i < 8; ++i) {
            if (de[i] >= 0) {
                int s = se[i], d = de[i];
                int pd = atomicAdd(&hd[d >> 8], 1);
                if (pd < CAPD)
                    bd[(size_t)(d >> 8) * CAPD + pd] = ((unsigned int)s << 8) | (d & 255);
                int ps = atomicAdd(&hs[s >> 8], 1);
                if (ps < CAPS)
                    bs[(size_t)(s >> 8) * CAPS + ps] = (unsigned char)(s & 255);
            }
        }
    } else if (b < A1 + A2 + B3) {
        // x fp32 -> bf16, 8 elems/thread, exact thread count.
        // Non-temporal loads: x is read exactly once; keep it out of L2 so it
        // doesn't evict partially-filled bucket lines (write-amp reduction).
        size_t tid = (size_t)(b - A1 - A2) * 1024 + t;
        const f32x4* xp = (const f32x4*)x;
        f32x4 a = __builtin_nontemporal_load(xp + tid * 2);
        f32x4 c = __builtin_nontemporal_load(xp + tid * 2 + 1);
        u32x4 o;
        o.x = pack2(a.x, a.y);
        o.y = pack2(a.z, a.w);
        o.z = pack2(c.x, c.y);
        o.w = pack2(c.z, c.w);
        ((u32x4*)xn)[tid] = o;
    } else {
        int w = b - (A1 + A2 + B3);          // 0..63; 32 blocks per weight
        int which = w >> 5;
        const float* W = which ? W2 : W1;
        unsigned short* out = which ? Bp2 : Bp1;
        int N = which ? F3 : F2;
        int idx = (w & 31) * 1024 + t;       // both weights have 32768 elems
        int k = idx / N, n = idx % N;
        unsigned short v = f2bf(W[idx]);
        int kt = k >> 5, q = (k >> 3) & 3, j = k & 7;
        int nt = n >> 4, lane = q * 16 + (n & 15);
        int NT = N >> 4;
        out[(((kt * NT + nt) * 64 + lane) << 3) + j] = v;
    }
}

// ---------------------------------------------------------------- kernel B
// one block per bucket. dst-buckets: padded CSR + cnt_in + rs_in.
// src-buckets: degree histogram -> rs_out.
__global__ __launch_bounds__(256) void bucket_build(
    const int* __restrict__ gcnt,
    const unsigned int* __restrict__ bkt_d1, const unsigned int* __restrict__ bkt_d2,
    const unsigned char* __restrict__ bkt_s1, const unsigned char* __restrict__ bkt_s2,
    int* __restrict__ csr1, int* __restrict__ cnt_in1, float* __restrict__ rs_in1,
    int* __restrict__ csr2, int* __restrict__ cnt_in2, float* __restrict__ rs_in2,
    float* __restrict__ rs_out1, float* __restrict__ rs_out2) {
    __shared__ int hist[256];
    int b = blockIdx.x, t = threadIdx.x;
    hist[t] = 0;
    __syncthreads();

    if (b < NB1D + NB2D) {
        const int L1 = (b < NB1D);
        int bb = L1 ? b : b - NB1D;
        const unsigned int* bkt = L1 ? bkt_d1 : bkt_d2;
        int* csr = L1 ? csr1 : csr2;
        int* cnt_in = L1 ? cnt_in1 : cnt_in2;
        float* rs_in = L1 ? rs_in1 : rs_in2;
        int Nd = L1 ? 100000 : 50000;
        int n = gcnt[(L1 ? GD1 : GD2) + bb];
        if (n > CAPD) n = CAPD;
        size_t base = (size_t)bb * CAPD;
        for (int i = t; i < n; i += 256) {
            unsigned int v = bkt[base + i];
            int d = v & 255, s = (int)(v >> 8);
            int pos = atomicAdd(&hist[d], 1);
            if (pos < CAP) csr[((size_t)(bb * 256 + d)) * CAP + pos] = s;
        }
        __syncthreads();
        int node = bb * 256 + t;
        if (node < Nd) {
            int c = hist[t];
            cnt_in[node] = c < CAP ? c : CAP;
            rs_in[node] = rsqrtf((float)(c < 1 ? 1 : c));
        }
    } else {
        const int L1 = (b < NB1D + NB2D + NB1S);
        int bb = L1 ? b - (NB1D + NB2D) : b - (NB1D + NB2D + NB1S);
        const unsigned char* bkt = L1 ? bkt_s1 : bkt_s2;
        float* rs_out = L1 ? rs_out1 : rs_out2;
        int Ns = L1 ? 200000 : 100000;
        int n = gcnt[(L1 ? GS1 : GS2) + bb];
        if (n > CAPS) n = CAPS;
        size_t base = (size_t)bb * CAPS;
        for (int i = t; i < n; i += 256) atomicAdd(&hist[bkt[base + i]], 1);
        __syncthreads();
        int node = bb * 256 + t;
        if (node < Ns) rs_out[node] = rsqrtf((float)(hist[t] < 1 ? 1 : hist[t]));
    }
}

// ---------------------------------------------------------------- gather aggregation
// F=128 bf16 rows, one wave per dst row. Lane layout: eg = lane>>4 picks one of
// 4 edges processed per iteration, fs = lane&15 picks a 16B feature slot.
// One uint4 gather per lane per iteration (4x fewer load instrs than 4B/lane),
// cross-edge-group reduction via 2 shfl_xor rounds at the end.
__global__ __launch_bounds__(256) void agg128_kernel(
    const unsigned int* __restrict__ X, const int* __restrict__ csr,
    const int* __restrict__ cnt, const float* __restrict__ rs_src,
    unsigned int* __restrict__ out, int ndst) {
    int wave = (int)((blockIdx.x * blockDim.x + threadIdx.x) >> 6);
    int lane = threadIdx.x & 63;
    if (wave >= ndst) return;
    size_t base = (size_t)wave * CAP;
    int len = cnt[wave];
    int eg = lane >> 4, fs = lane & 15;
    float acc[8];
#pragma unroll
    for (int i = 0; i < 8; ++i) acc[i] = 0.f;
    for (int j = 0; j < len; j += 4) {
        int jj = j + eg;
        int ok = jj < len;
        int s = csr[base + (ok ? jj : 0)];
        float c = ok ? rs_src[s] : 0.f;
        u32x4 u = *(const u32x4*)(X + (size_t)s * 64 + (fs << 2));
        acc[0] = fmaf(c, bf2f(u.x & 0xffff), acc[0]);
        acc[1] = fmaf(c, bf2f(u.x >> 16), acc[1]);
        acc[2] = fmaf(c, bf2f(u.y & 0xffff), acc[2]);
        acc[3] = fmaf(c, bf2f(u.y >> 16), acc[3]);
        acc[4] = fmaf(c, bf2f(u.z & 0xffff), acc[4]);
        acc[5] = fmaf(c, bf2f(u.z >> 16), acc[5]);
        acc[6] = fmaf(c, bf2f(u.w & 0xffff), acc[6]);
        acc[7] = fmaf(c, bf2f(u.w >> 16), acc[7]);
    }
#pragma unroll
    for (int i = 0; i < 8; ++i) {
        acc[i] += __shfl_xor(acc[i], 16);
        acc[i] += __shfl_xor(acc[i], 32);
    }
    if (eg == 0) {
        u32x4 o;
        o.x = pack2(acc[0], acc[1]);
        o.y = pack2(acc[2], acc[3]);
        o.z = pack2(acc[4], acc[5]);
        o.w = pack2(acc[6], acc[7]);
        *((u32x4*)(out + (size_t)wave * 64) + fs) = o;
    }
}

// ---------------------------------------------------------------- fused two-stage GEMM
// stage1: tmp = relu(rs1[m]*(A@W1)+b1)*rs2[m]  (128x256 bf16, LDS)
// stage2: Y = tmp @ W2                          (128x128 bf16, global)
// 32 rows per wave (two 16-row A fragments share each B fragment) -> halves
// the per-row B-fragment L2 traffic vs 16 rows/wave.
__global__ __launch_bounds__(256) void gemm12(
    const unsigned short* __restrict__ A,    // agg [M,128] bf16
    const unsigned short* __restrict__ Bp1,  // W1 fragments (K=128,N=256)
    const unsigned short* __restrict__ Bp2,  // W2 fragments (K=256,N=128)
    const float* __restrict__ rs1, const float* __restrict__ rs2,
    const float* __restrict__ bias1,
    unsigned short* __restrict__ Y, int M) {
    __shared__ unsigned short tmp[128][264];  // +8 pad, 67.6 KB -> 2 blocks/CU
    int lane = threadIdx.x & 63, wid = threadIdx.x >> 6;
    int row0 = blockIdx.x * 128 + wid * 32;
    int q = lane >> 4, col = lane & 15;

    // ---- stage 1: 32 rows x 256 cols per wave
    int m0 = row0 + col;
    if (m0 > M - 1) m0 = M - 1;
    int m1 = row0 + 16 + col;
    if (m1 > M - 1) m1 = M - 1;
    const unsigned short* Ar0 = A + (size_t)m0 * F1 + q * 8;
    const unsigned short* Ar1 = A + (size_t)m1 * F1 + q * 8;
    f32x4 acc0[16], acc1[16];
#pragma unroll
    for (int i = 0; i < 16; ++i) {
        acc0[i] = (f32x4){0.f, 0.f, 0.f, 0.f};
        acc1[i] = (f32x4){0.f, 0.f, 0.f, 0.f};
    }
#pragma unroll
    for (int kt = 0; kt < 4; ++kt) {
        bf16x8 a0 = *(const bf16x8*)(Ar0 + kt * 32);
        bf16x8 a1 = *(const bf16x8*)(Ar1 + kt * 32);
#pragma unroll
        for (int nt = 0; nt < 16; ++nt) {
            bf16x8 bfr = *(const bf16x8*)(Bp1 + (((kt * 16 + nt) * 64 + lane) << 3));
            acc0[nt] = __builtin_amdgcn_mfma_f32_16x16x32_bf16(a0, bfr, acc0[nt], 0, 0, 0);
            acc1[nt] = __builtin_amdgcn_mfma_f32_16x16x32_bf16(a1, bfr, acc1[nt], 0, 0, 0);
        }
    }
#pragma unroll
    for (int r = 0; r < 4; ++r) {
        int lrow = wid * 32 + q * 4 + r;
        int ma = row0 + q * 4 + r;
        int mca = ma < M ? ma : M - 1;
        float s1a = rs1[mca], s2a = rs2[mca];
        int mb = ma + 16;
        int mcb = mb < M ? mb : M - 1;
        float s1b = rs1[mcb], s2b = rs2[mcb];
#pragma unroll
        for (int nt = 0; nt < 16; ++nt) {
            float bsv = bias1[nt * 16 + col];
            tmp[lrow][nt * 16 + col] =
                f2bf(fmaxf(fmaf(acc0[nt][r], s1a, bsv), 0.f) * s2a);
            tmp[lrow + 16][nt * 16 + col] =
                f2bf(fmaxf(fmaf(acc1[nt][r], s1b, bsv), 0.f) * s2b);
        }
    }
    __syncthreads();

    // ---- stage 2: same 32 rows x 128 cols, K=256 from tmp
    f32x4 acc2a[8], acc2b[8];
#pragma unroll
    for (int i = 0; i < 8; ++i) {
        acc2a[i] = (f32x4){0.f, 0.f, 0.f, 0.f};
        acc2b[i] = (f32x4){0.f, 0.f, 0.f, 0.f};
    }
    const unsigned short* t0 = &tmp[wid * 32 + col][q * 8];
    const unsigned short* t1 = &tmp[wid * 32 + 16 + col][q * 8];
#pragma unroll
    for (int kt = 0; kt < 8; ++kt) {
        bf16x8 a0 = *(const bf16x8*)(t0 + kt * 32);
        bf16x8 a1 = *(const bf16x8*)(t1 + kt * 32);
#pragma unroll
        for (int nt = 0; nt < 8; ++nt) {
            bf16x8 bfr = *(const bf16x8*)(Bp2 + (((kt * 8 + nt) * 64 + lane) << 3));
            acc2a[nt] = __builtin_amdgcn_mfma_f32_16x16x32_bf16(a0, bfr, acc2a[nt], 0, 0, 0);
            acc2b[nt] = __builtin_amdgcn_mfma_f32_16x16x32_bf16(a1, bfr, acc2b[nt], 0, 0, 0);
        }
    }
#pragma unroll
    for (int r = 0; r < 4; ++r) {
        int ma = row0 + q * 4 + r;
        if (ma < M) {
#pragma unroll
            for (int nt = 0; nt < 8; ++nt)
                Y[(size_t)ma * F3 + nt * 16 + col] = f2bf(acc2a[nt][r]);
        }
        int mb = ma + 16;
        if (mb < M) {
#pragma unroll
            for (int nt = 0; nt < 8; ++nt)
                Y[(size_t)mb * F3 + nt * 16 + col] = f2bf(acc2b[nt][r]);
        }
    }
}

// ---------------------------------------------------------------- final aggregation
// gather y rows (128 bf16), sum, out = relu(rs_in2[d]*sum + b2) -> fp32
// Same eg/fs lane layout as agg128_kernel.
__global__ __launch_bounds__(256) void agg_final(
    const unsigned int* __restrict__ Yv, const int* __restrict__ csr,
    const int* __restrict__ cnt, const float* __restrict__ rs_dst,
    const float* __restrict__ b2, float* __restrict__ out, int ndst) {
    int wave = (int)((blockIdx.x * blockDim.x + threadIdx.x) >> 6);
    int lane = threadIdx.x & 63;
    if (wave >= ndst) return;
    size_t base = (size_t)wave * CAP;
    int len = cnt[wave];
    int eg = lane >> 4, fs = lane & 15;
    float acc[8];
#pragma unroll
    for (int i = 0; i < 8; ++i) acc[i] = 0.f;
    for (int j = 0; j < len; j += 4) {
        int jj = j + eg;
        int ok = jj < len;
        int s = csr[base + (ok ? jj : 0)];
        float c = ok ? 1.f : 0.f;
        u32x4 u = *(const u32x4*)(Yv + (size_t)s * 64 + (fs << 2));
        acc[0] = fmaf(c, bf2f(u.x & 0xffff), acc[0]);
        acc[1] = fmaf(c, bf2f(u.x >> 16), acc[1]);
        acc[2] = fmaf(c, bf2f(u.y & 0xffff), acc[2]);
        acc[3] = fmaf(c, bf2f(u.y >> 16), acc[3]);
        acc[4] = fmaf(c, bf2f(u.z & 0xffff), acc[4]);
        acc[5] = fmaf(c, bf2f(u.z >> 16), acc[5]);
        acc[6] = fmaf(c, bf2f(u.w & 0xffff), acc[6]);
        acc[7] = fmaf(c, bf2f(u.w >> 16), acc[7]);
    }
#pragma unroll
    for (int i = 0; i < 8; ++i) {
        acc[i] += __shfl_xor(acc[i], 16);
        acc[i] += __shfl_xor(acc[i], 32);
    }
    if (eg < 2) {
        float sc = rs_dst[wave];
        f32x4 bias = ((const f32x4*)b2)[(fs << 1) | eg];
        // static-index selection (no runtime-indexed register array)
        float v0 = eg ? acc[4] : acc[0];
        float v1 = eg ? acc[5] : acc[1];
        float v2 = eg ? acc[6] : acc[2];
        float v3 = eg ? acc[7] : acc[3];
        f32x4 o;
        o.x = fmaxf(fmaf(v0, sc, bias.x), 0.f);
        o.y = fmaxf(fmaf(v1, sc, bias.y), 0.f);
        o.z = fmaxf(fmaf(v2, sc, bias.z), 0.f);
        o.w = fmaxf(fmaf(v3, sc, bias.w), 0.f);
        __builtin_nontemporal_store(o, (f32x4*)out + (size_t)wave * 32 + (fs << 1) + eg);
    }
}

extern "C" void kernel_launch(void* const* d_in, const int* in_sizes, int n_in,
                              void* d_out, int out_size, void* d_ws, size_t ws_size,
                              hipStream_t stream) {
    const float* x  = (const float*)d_in[0];
    const float* W1 = (const float*)d_in[1];
    const float* b1 = (const float*)d_in[2];
    const float* W2 = (const float*)d_in[3];
    const float* b2 = (const float*)d_in[4];
    const int* src1 = (const int*)d_in[5];
    const int* dst1 = (const int*)d_in[6];
    const int* src2 = (const int*)d_in[7];
    const int* dst2 = (const int*)d_in[8];
    const int E1 = in_sizes[5], E2 = in_sizes[7];
    const int N0 = in_sizes[0] / F1;  // 200000
    const int N1 = 100000, N2 = 50000;

    // ---- workspace layout (all segment sizes multiples of 16 B)
    char* p = (char*)d_ws;
    int* gcnt = (int*)p; p += 2048 * 4;                          // 1760 used
    float* rs_out1 = (float*)p; p += (size_t)N0 * 4;
    float* rs_in1  = (float*)p; p += (size_t)N1 * 4;
    float* rs_out2 = (float*)p; p += (size_t)N1 * 4;
    float* rs_in2  = (float*)p; p += (size_t)N2 * 4;
    int* cnt_in1 = (int*)p; p += (size_t)N1 * 4;
    int* cnt_in2 = (int*)p; p += (size_t)N2 * 4;
    unsigned int* bkt_d1 = (unsigned int*)p; p += (size_t)NB1D * CAPD * 4;  // 7.2 MB
    unsigned int* bkt_d2 = (unsigned int*)p; p += (size_t)NB2D * CAPD * 4;  // 3.6 MB
    unsigned char* bkt_s1 = (unsigned char*)p; p += (size_t)NB1S * CAPS;    // 1.9 MB
    unsigned char* bkt_s2 = (unsigned char*)p; p += (size_t)NB2S * CAPS;    // 1.0 MB
    int* csr1 = (int*)p; p += (size_t)N1 * CAP * 4;              // 25.6 MB
    int* csr2 = (int*)p; p += (size_t)N2 * CAP * 4;              // 12.8 MB
    unsigned short* Bp1 = (unsigned short*)p; p += (size_t)F1 * F2 * 2;
    unsigned short* Bp2 = (unsigned short*)p; p += (size_t)F2 * F3 * 2;
    unsigned short* xn  = (unsigned short*)p; p += (size_t)N0 * F1 * 2;  // 51.2 MB
    unsigned short* agg = (unsigned short*)p; p += (size_t)N1 * F1 * 2;  // 25.6 MB
    // y aliases xn: xn (25.6M elems) dead after agg128; y (N1*F3=12.8M elems) born at gemm12
    unsigned short* y = xn;

    (void)hipMemsetAsync(gcnt, 0, 2048 * 4, stream);

    // kernel A: bucket scatter (both layers) + x->bf16 + weight permutes
    int A1 = (E1 + 8191) / 8192;
    int A2 = (E2 + 8191) / 8192;
    int B3 = N0 * F1 / 8 / 1024;  // exact: 3125
    scatter_build<<<A1 + A2 + B3 + 64, 1024, 0, stream>>>(
        src1, dst1, src2, dst2, x, W1, W2, gcnt,
        bkt_d1, bkt_d2, bkt_s1, bkt_s2,
        (unsigned int*)xn, Bp1, Bp2, E1, E2, A1, A2, B3);

    // kernel B: per-bucket CSR + degree norms
    bucket_build<<<NB1D + NB2D + NB1S + NB2S, 256, 0, stream>>>(
        gcnt, bkt_d1, bkt_d2, bkt_s1, bkt_s2,
        csr1, cnt_in1, rs_in1, csr2, cnt_in2, rs_in2, rs_out1, rs_out2);

    // layer 1 aggregation (per-edge src norm)
    agg128_kernel<<<(N1 + 3) / 4, 256, 0, stream>>>((const unsigned int*)xn, csr1,
                                                    cnt_in1, rs_out1,
                                                    (unsigned int*)agg, N1);

    // fused: hn = relu(rs_in1*(agg@W1)+b1)*rs_out2 ; y = hn@W2
    gemm12<<<(N1 + 127) / 128, 256, 0, stream>>>(agg, Bp1, Bp2, rs_in1, rs_out2, b1, y, N1);

    // layer 2 aggregation + fused epilogue: out = relu(rs_in2*segsum(y) + b2)
    agg_final<<<(N2 + 3) / 4, 256, 0, stream>>>((const unsigned int*)y, csr2, cnt_in2,
                                                rs_in2, b2, (float*)d_out, N2);
}

// Round 3
// 377.494 us; speedup vs baseline: 1.1705x; 1.1705x over previous
//
#include <hip/hip_runtime.h>
#include <hip/hip_bf16.h>

#define F1 128
#define F2 256
#define F3 128
#define CAP 64

// bucket geometry: 256 nodes per bucket
#define NB1D 391   // ceil(100000/256) dst1 buckets
#define NB2D 196   // ceil(50000/256)  dst2 buckets
#define NB1S 782   // ceil(200000/256) src1 buckets
#define NB2S 391   // ceil(100000/256) src2 buckets
#define CAPD 4608  // dst-bucket capacity (mean ~4092, sd ~64 -> 8 sigma)
#define CAPS 2432  // src-bucket capacity (mean ~2046, sd ~45 -> 8.5 sigma)
// gcnt layout offsets
#define GD1 0
#define GD2 391
#define GS1 587
#define GS2 1369

typedef __attribute__((ext_vector_type(8))) short bf16x8;
typedef __attribute__((ext_vector_type(4))) float f32x4;
typedef __attribute__((ext_vector_type(4))) unsigned int u32x4;

__device__ inline float bf2f(unsigned short u) {
    return __uint_as_float(((unsigned int)u) << 16);
}
__device__ inline unsigned short f2bf(float f) {
    __hip_bfloat16 b = __float2bfloat16(f);
    return *reinterpret_cast<unsigned short*>(&b);
}
__device__ inline unsigned int pack2(float lo, float hi) {
    return ((unsigned int)f2bf(hi) << 16) | f2bf(lo);
}

// ---------------------------------------------------------------- kernel A (1024 thr)
// block ranges: [0,A1) L1 edge scatter (8192 edges, 8 iters), [A1,A1+A2) L2,
// [+B3) x fp32->bf16 (8192 elems/block), [+64) weight permutes (32 blocks each).
__global__ __launch_bounds__(1024) void scatter_build(
    const int* __restrict__ src1, const int* __restrict__ dst1,
    const int* __restrict__ src2, const int* __restrict__ dst2,
    const float* __restrict__ x, const float* __restrict__ W1,
    const float* __restrict__ W2, int* __restrict__ gcnt,
    unsigned int* __restrict__ bkt_d1, unsigned int* __restrict__ bkt_d2,
    unsigned char* __restrict__ bkt_s1, unsigned char* __restrict__ bkt_s2,
    unsigned int* __restrict__ xn, unsigned short* __restrict__ Bp1,
    unsigned short* __restrict__ Bp2, int E1, int E2, int A1, int A2, int B3) {
    __shared__ int hist[1184];  // >= NB1D + NB1S = 1173
    int b = blockIdx.x, t = threadIdx.x;

    if (b < A1 + A2) {
        const int L1 = (b < A1);
        const int* __restrict__ src = L1 ? src1 : src2;
        const int* __restrict__ dst = L1 ? dst1 : dst2;
        const int E = L1 ? E1 : E2;
        const int NBd = L1 ? NB1D : NB2D;
        const int NBs = L1 ? NB1S : NB2S;
        int* gd = gcnt + (L1 ? GD1 : GD2);
        int* gs = gcnt + (L1 ? GS1 : GS2);
        unsigned int* bd = L1 ? bkt_d1 : bkt_d2;
        unsigned char* bs = L1 ? bkt_s1 : bkt_s2;
        int* hd = hist;
        int* hs = hist + NBd;
        for (int i = t; i < NBd + NBs; i += 1024) hist[i] = 0;
        __syncthreads();
        int e0 = (L1 ? b : b - A1) * 8192;
        // pass 1: local histograms; cache edges in registers for pass 2
        int se[8], de[8];
#pragma unroll
        for (int i = 0; i < 8; ++i) {
            int e = e0 + i * 1024 + t;
            se[i] = -1;
            de[i] = -1;
            if (e < E) {
                int s = src[e], d = dst[e];
                se[i] = s;
                de[i] = d;
                atomicAdd(&hd[d >> 8], 1);
                atomicAdd(&hs[s >> 8], 1);
            }
        }
        __syncthreads();
        // reserve global space; hist becomes cursor (global base)
        for (int i = t; i < NBd; i += 1024) {
            int c = hd[i];
            hd[i] = c ? atomicAdd(&gd[i], c) : 0;
        }
        for (int i = t; i < NBs; i += 1024) {
            int c = hs[i];
            hs[i] = c ? atomicAdd(&gs[i], c) : 0;
        }
        __syncthreads();
        // pass 2: scatter into buckets (runs contiguous per (block,bucket))
#pragma unroll
        for (int i = 0; i < 8; ++i) {
            if (de[i] >= 0) {
                int s = se[i], d = de[i];
                int pd = atomicAdd(&hd[d >> 8], 1);
                if (pd < CAPD)
                    bd[(size_t)(d >> 8) * CAPD + pd] = ((unsigned int)s << 8) | (d & 255);
                int ps = atomicAdd(&hs[s >> 8], 1);
                if (ps < CAPS)
                    bs[(size_t)(s >> 8) * CAPS + ps] = (unsigned char)(s & 255);
            }
        }
    } else if (b < A1 + A2 + B3) {
        // x fp32 -> bf16, 8 elems/thread, exact thread count.
        // Non-temporal loads: x is read exactly once; keep it out of L2 so it
        // doesn't evict partially-filled bucket lines (write-amp reduction).
        size_t tid = (size_t)(b - A1 - A2) * 1024 + t;
        const f32x4* xp = (const f32x4*)x;
        f32x4 a = __builtin_nontemporal_load(xp + tid * 2);
        f32x4 c = __builtin_nontemporal_load(xp + tid * 2 + 1);
        u32x4 o;
        o.x = pack2(a.x, a.y);
        o.y = pack2(a.z, a.w);
        o.z = pack2(c.x, c.y);
        o.w = pack2(c.z, c.w);
        ((u32x4*)xn)[tid] = o;
    } else {
        int w = b - (A1 + A2 + B3);          // 0..63; 32 blocks per weight
        int which = w >> 5;
        const float* W = which ? W2 : W1;
        unsigned short* out = which ? Bp2 : Bp1;
        int N = which ? F3 : F2;
        int idx = (w & 31) * 1024 + t;       // both weights have 32768 elems
        int k = idx / N, n = idx % N;
        unsigned short v = f2bf(W[idx]);
        int kt = k >> 5, q = (k >> 3) & 3, j = k & 7;
        int nt = n >> 4, lane = q * 16 + (n & 15);
        int NT = N >> 4;
        out[(((kt * NT + nt) * 64 + lane) << 3) + j] = v;
    }
}

// ---------------------------------------------------------------- kernel B
// one block per bucket. dst-buckets: padded CSR + cnt_in + rs_in.
// src-buckets: degree histogram -> rs_out.
__global__ __launch_bounds__(256) void bucket_build(
    const int* __restrict__ gcnt,
    const unsigned int* __restrict__ bkt_d1, const unsigned int* __restrict__ bkt_d2,
    const unsigned char* __restrict__ bkt_s1, const unsigned char* __restrict__ bkt_s2,
    int* __restrict__ csr1, int* __restrict__ cnt_in1, float* __restrict__ rs_in1,
    int* __restrict__ csr2, int* __restrict__ cnt_in2, float* __restrict__ rs_in2,
    float* __restrict__ rs_out1, float* __restrict__ rs_out2) {
    __shared__ int hist[256];
    int b = blockIdx.x, t = threadIdx.x;
    hist[t] = 0;
    __syncthreads();

    if (b < NB1D + NB2D) {
        const int L1 = (b < NB1D);
        int bb = L1 ? b : b - NB1D;
        const unsigned int* bkt = L1 ? bkt_d1 : bkt_d2;
        int* csr = L1 ? csr1 : csr2;
        int* cnt_in = L1 ? cnt_in1 : cnt_in2;
        float* rs_in = L1 ? rs_in1 : rs_in2;
        int Nd = L1 ? 100000 : 50000;
        int n = gcnt[(L1 ? GD1 : GD2) + bb];
        if (n > CAPD) n = CAPD;
        size_t base = (size_t)bb * CAPD;
        for (int i = t; i < n; i += 256) {
            unsigned int v = bkt[base + i];
            int d = v & 255, s = (int)(v >> 8);
            int pos = atomicAdd(&hist[d], 1);
            if (pos < CAP) csr[((size_t)(bb * 256 + d)) * CAP + pos] = s;
        }
        __syncthreads();
        int node = bb * 256 + t;
        if (node < Nd) {
            int c = hist[t];
            cnt_in[node] = c < CAP ? c : CAP;
            rs_in[node] = rsqrtf((float)(c < 1 ? 1 : c));
        }
    } else {
        const int L1 = (b < NB1D + NB2D + NB1S);
        int bb = L1 ? b - (NB1D + NB2D) : b - (NB1D + NB2D + NB1S);
        const unsigned char* bkt = L1 ? bkt_s1 : bkt_s2;
        float* rs_out = L1 ? rs_out1 : rs_out2;
        int Ns = L1 ? 200000 : 100000;
        int n = gcnt[(L1 ? GS1 : GS2) + bb];
        if (n > CAPS) n = CAPS;
        size_t base = (size_t)bb * CAPS;
        for (int i = t; i < n; i += 256) atomicAdd(&hist[bkt[base + i]], 1);
        __syncthreads();
        int node = bb * 256 + t;
        if (node < Ns) rs_out[node] = rsqrtf((float)(hist[t] < 1 ? 1 : hist[t]));
    }
}

// ---------------------------------------------------------------- gather aggregation
// F=128 bf16 rows, one wave per dst row. Lane layout: eg = lane>>4 picks one of
// 4 edges processed per iteration, fs = lane&15 picks a 16B feature slot.
// One uint4 gather per lane per iteration (4x fewer load instrs than 4B/lane),
// cross-edge-group reduction via 2 shfl_xor rounds at the end.
__global__ __launch_bounds__(256) void agg128_kernel(
    const unsigned int* __restrict__ X, const int* __restrict__ csr,
    const int* __restrict__ cnt, const float* __restrict__ rs_src,
    unsigned int* __restrict__ out, int ndst) {
    int wave = (int)((blockIdx.x * blockDim.x + threadIdx.x) >> 6);
    int lane = threadIdx.x & 63;
    if (wave >= ndst) return;
    size_t base = (size_t)wave * CAP;
    int len = cnt[wave];
    int eg = lane >> 4, fs = lane & 15;
    float acc[8];
#pragma unroll
    for (int i = 0; i < 8; ++i) acc[i] = 0.f;
    for (int j = 0; j < len; j += 4) {
        int jj = j + eg;
        int ok = jj < len;
        int s = csr[base + (ok ? jj : 0)];
        float c = ok ? rs_src[s] : 0.f;
        u32x4 u = *(const u32x4*)(X + (size_t)s * 64 + (fs << 2));
        acc[0] = fmaf(c, bf2f(u.x & 0xffff), acc[0]);
        acc[1] = fmaf(c, bf2f(u.x >> 16), acc[1]);
        acc[2] = fmaf(c, bf2f(u.y & 0xffff), acc[2]);
        acc[3] = fmaf(c, bf2f(u.y >> 16), acc[3]);
        acc[4] = fmaf(c, bf2f(u.z & 0xffff), acc[4]);
        acc[5] = fmaf(c, bf2f(u.z >> 16), acc[5]);
        acc[6] = fmaf(c, bf2f(u.w & 0xffff), acc[6]);
        acc[7] = fmaf(c, bf2f(u.w >> 16), acc[7]);
    }
#pragma unroll
    for (int i = 0; i < 8; ++i) {
        acc[i] += __shfl_xor(acc[i], 16);
        acc[i] += __shfl_xor(acc[i], 32);
    }
    if (eg == 0) {
        u32x4 o;
        o.x = pack2(acc[0], acc[1]);
        o.y = pack2(acc[2], acc[3]);
        o.z = pack2(acc[4], acc[5]);
        o.w = pack2(acc[6], acc[7]);
        *((u32x4*)(out + (size_t)wave * 64) + fs) = o;
    }
}

// ---------------------------------------------------------------- fused two-stage GEMM
// 512 threads = 8 waves x 16 rows = 128-row tile.
// B matrices staged in LDS (they are shared by every wave of every block):
//   phase 0: coop-copy Bp1 (64 KB) global->LDS
//   stage 1: tmp = relu(rs1[m]*(A@W1)+b1)*rs2[m]   (B from LDS, conflict-free b128)
//   phase 2: coop-copy Bp2 (64 KB) over the same LDS region
//   stage 2: Y = tmp @ W2                           (B from LDS)
// Fixes round-1 regression: B-fragment loads were serialized global/L2
// round-trips (MfmaUtil 4.4%, all pipes idle). LDS total 130 KB -> 1 block/CU.
__global__ __launch_bounds__(512) void gemm12(
    const unsigned short* __restrict__ A,    // agg [M,128] bf16
    const unsigned short* __restrict__ Bp1,  // W1 fragments (K=128,N=256)
    const unsigned short* __restrict__ Bp2,  // W2 fragments (K=256,N=128)
    const float* __restrict__ rs1, const float* __restrict__ rs2,
    const float* __restrict__ bias1,
    unsigned short* __restrict__ Y, int M) {
    __shared__ unsigned short Bs[32768];      // 64 KB, holds Bp1 then Bp2
    __shared__ unsigned short tmp[128][264];  // +8 pad, 67.6 KB
    int lane = threadIdx.x & 63, wid = threadIdx.x >> 6;
    int t = threadIdx.x;
    int row0 = blockIdx.x * 128 + wid * 16;
    int q = lane >> 4, col = lane & 15;

    // ---- phase 0: Bp1 -> LDS (4096 uint4 / 512 threads = 8 iters)
#pragma unroll
    for (int i = 0; i < 8; ++i)
        ((u32x4*)Bs)[i * 512 + t] = ((const u32x4*)Bp1)[i * 512 + t];
    __syncthreads();

    // ---- stage 1: 16 rows x 256 cols per wave
    int mload = row0 + col;
    if (mload > M - 1) mload = M - 1;
    const unsigned short* Arow = A + (size_t)mload * F1 + q * 8;
    f32x4 acc[16];
#pragma unroll
    for (int i = 0; i < 16; ++i) acc[i] = (f32x4){0.f, 0.f, 0.f, 0.f};
#pragma unroll
    for (int kt = 0; kt < 4; ++kt) {
        bf16x8 a = *(const bf16x8*)(Arow + kt * 32);
#pragma unroll
        for (int nt = 0; nt < 16; ++nt) {
            bf16x8 b = *(const bf16x8*)(Bs + (((kt * 16 + nt) * 64 + lane) << 3));
            acc[nt] = __builtin_amdgcn_mfma_f32_16x16x32_bf16(a, b, acc[nt], 0, 0, 0);
        }
    }
#pragma unroll
    for (int r = 0; r < 4; ++r) {
        int lrow = wid * 16 + q * 4 + r;
        int m = row0 + q * 4 + r;
        int mc = m < M ? m : M - 1;
        float s1 = rs1[mc], s2 = rs2[mc];
#pragma unroll
        for (int nt = 0; nt < 16; ++nt) {
            float v = fmaxf(fmaf(acc[nt][r], s1, bias1[nt * 16 + col]), 0.f) * s2;
            tmp[lrow][nt * 16 + col] = f2bf(v);
        }
    }
    __syncthreads();

    // ---- phase 2: Bp2 -> LDS (overwrite Bp1 region)
#pragma unroll
    for (int i = 0; i < 8; ++i)
        ((u32x4*)Bs)[i * 512 + t] = ((const u32x4*)Bp2)[i * 512 + t];
    __syncthreads();

    // ---- stage 2: same 16 rows x 128 cols, K=256 from tmp
    f32x4 acc2[8];
#pragma unroll
    for (int i = 0; i < 8; ++i) acc2[i] = (f32x4){0.f, 0.f, 0.f, 0.f};
    const unsigned short* trow = &tmp[wid * 16 + col][q * 8];
#pragma unroll
    for (int kt = 0; kt < 8; ++kt) {
        bf16x8 a = *(const bf16x8*)(trow + kt * 32);
#pragma unroll
        for (int nt = 0; nt < 8; ++nt) {
            bf16x8 b = *(const bf16x8*)(Bs + (((kt * 8 + nt) * 64 + lane) << 3));
            acc2[nt] = __builtin_amdgcn_mfma_f32_16x16x32_bf16(a, b, acc2[nt], 0, 0, 0);
        }
    }
#pragma unroll
    for (int r = 0; r < 4; ++r) {
        int m = row0 + q * 4 + r;
        if (m >= M) continue;
#pragma unroll
        for (int nt = 0; nt < 8; ++nt)
            Y[(size_t)m * F3 + nt * 16 + col] = f2bf(acc2[nt][r]);
    }
}

// ---------------------------------------------------------------- final aggregation
// gather y rows (128 bf16), sum, out = relu(rs_in2[d]*sum + b2) -> fp32
// Same eg/fs lane layout as agg128_kernel.
__global__ __launch_bounds__(256) void agg_final(
    const unsigned int* __restrict__ Yv, const int* __restrict__ csr,
    const int* __restrict__ cnt, const float* __restrict__ rs_dst,
    const float* __restrict__ b2, float* __restrict__ out, int ndst) {
    int wave = (int)((blockIdx.x * blockDim.x + threadIdx.x) >> 6);
    int lane = threadIdx.x & 63;
    if (wave >= ndst) return;
    size_t base = (size_t)wave * CAP;
    int len = cnt[wave];
    int eg = lane >> 4, fs = lane & 15;
    float acc[8];
#pragma unroll
    for (int i = 0; i < 8; ++i) acc[i] = 0.f;
    for (int j = 0; j < len; j += 4) {
        int jj = j + eg;
        int ok = jj < len;
        int s = csr[base + (ok ? jj : 0)];
        float c = ok ? 1.f : 0.f;
        u32x4 u = *(const u32x4*)(Yv + (size_t)s * 64 + (fs << 2));
        acc[0] = fmaf(c, bf2f(u.x & 0xffff), acc[0]);
        acc[1] = fmaf(c, bf2f(u.x >> 16), acc[1]);
        acc[2] = fmaf(c, bf2f(u.y & 0xffff), acc[2]);
        acc[3] = fmaf(c, bf2f(u.y >> 16), acc[3]);
        acc[4] = fmaf(c, bf2f(u.z & 0xffff), acc[4]);
        acc[5] = fmaf(c, bf2f(u.z >> 16), acc[5]);
        acc[6] = fmaf(c, bf2f(u.w & 0xffff), acc[6]);
        acc[7] = fmaf(c, bf2f(u.w >> 16), acc[7]);
    }
#pragma unroll
    for (int i = 0; i < 8; ++i) {
        acc[i] += __shfl_xor(acc[i], 16);
        acc[i] += __shfl_xor(acc[i], 32);
    }
    if (eg < 2) {
        float sc = rs_dst[wave];
        f32x4 bias = ((const f32x4*)b2)[(fs << 1) | eg];
        // static-index selection (no runtime-indexed register array)
        float v0 = eg ? acc[4] : acc[0];
        float v1 = eg ? acc[5] : acc[1];
        float v2 = eg ? acc[6] : acc[2];
        float v3 = eg ? acc[7] : acc[3];
        f32x4 o;
        o.x = fmaxf(fmaf(v0, sc, bias.x), 0.f);
        o.y = fmaxf(fmaf(v1, sc, bias.y), 0.f);
        o.z = fmaxf(fmaf(v2, sc, bias.z), 0.f);
        o.w = fmaxf(fmaf(v3, sc, bias.w), 0.f);
        __builtin_nontemporal_store(o, (f32x4*)out + (size_t)wave * 32 + (fs << 1) + eg);
    }
}

extern "C" void kernel_launch(void* const* d_in, const int* in_sizes, int n_in,
                              void* d_out, int out_size, void* d_ws, size_t ws_size,
                              hipStream_t stream) {
    const float* x  = (const float*)d_in[0];
    const float* W1 = (const float*)d_in[1];
    const float* b1 = (const float*)d_in[2];
    const float* W2 = (const float*)d_in[3];
    const float* b2 = (const float*)d_in[4];
    const int* src1 = (const int*)d_in[5];
    const int* dst1 = (const int*)d_in[6];
    const int* src2 = (const int*)d_in[7];
    const int* dst2 = (const int*)d_in[8];
    const int E1 = in_sizes[5], E2 = in_sizes[7];
    const int N0 = in_sizes[0] / F1;  // 200000
    const int N1 = 100000, N2 = 50000;

    // ---- workspace layout (all segment sizes multiples of 16 B)
    char* p = (char*)d_ws;
    int* gcnt = (int*)p; p += 2048 * 4;                          // 1760 used
    float* rs_out1 = (float*)p; p += (size_t)N0 * 4;
    float* rs_in1  = (float*)p; p += (size_t)N1 * 4;
    float* rs_out2 = (float*)p; p += (size_t)N1 * 4;
    float* rs_in2  = (float*)p; p += (size_t)N2 * 4;
    int* cnt_in1 = (int*)p; p += (size_t)N1 * 4;
    int* cnt_in2 = (int*)p; p += (size_t)N2 * 4;
    unsigned int* bkt_d1 = (unsigned int*)p; p += (size_t)NB1D * CAPD * 4;  // 7.2 MB
    unsigned int* bkt_d2 = (unsigned int*)p; p += (size_t)NB2D * CAPD * 4;  // 3.6 MB
    unsigned char* bkt_s1 = (unsigned char*)p; p += (size_t)NB1S * CAPS;    // 1.9 MB
    unsigned char* bkt_s2 = (unsigned char*)p; p += (size_t)NB2S * CAPS;    // 1.0 MB
    int* csr1 = (int*)p; p += (size_t)N1 * CAP * 4;              // 25.6 MB
    int* csr2 = (int*)p; p += (size_t)N2 * CAP * 4;              // 12.8 MB
    unsigned short* Bp1 = (unsigned short*)p; p += (size_t)F1 * F2 * 2;
    unsigned short* Bp2 = (unsigned short*)p; p += (size_t)F2 * F3 * 2;
    unsigned short* xn  = (unsigned short*)p; p += (size_t)N0 * F1 * 2;  // 51.2 MB
    unsigned short* agg = (unsigned short*)p; p += (size_t)N1 * F1 * 2;  // 25.6 MB
    // y aliases xn: xn (25.6M elems) dead after agg128; y (N1*F3=12.8M elems) born at gemm12
    unsigned short* y = xn;

    (void)hipMemsetAsync(gcnt, 0, 2048 * 4, stream);

    // kernel A: bucket scatter (both layers) + x->bf16 + weight permutes
    int A1 = (E1 + 8191) / 8192;
    int A2 = (E2 + 8191) / 8192;
    int B3 = N0 * F1 / 8 / 1024;  // exact: 3125
    scatter_build<<<A1 + A2 + B3 + 64, 1024, 0, stream>>>(
        src1, dst1, src2, dst2, x, W1, W2, gcnt,
        bkt_d1, bkt_d2, bkt_s1, bkt_s2,
        (unsigned int*)xn, Bp1, Bp2, E1, E2, A1, A2, B3);

    // kernel B: per-bucket CSR + degree norms
    bucket_build<<<NB1D + NB2D + NB1S + NB2S, 256, 0, stream>>>(
        gcnt, bkt_d1, bkt_d2, bkt_s1, bkt_s2,
        csr1, cnt_in1, rs_in1, csr2, cnt_in2, rs_in2, rs_out1, rs_out2);

    // layer 1 aggregation (per-edge src norm)
    agg128_kernel<<<(N1 + 3) / 4, 256, 0, stream>>>((const unsigned int*)xn, csr1,
                                                    cnt_in1, rs_out1,
                                                    (unsigned int*)agg, N1);

    // fused: hn = relu(rs_in1*(agg@W1)+b1)*rs_out2 ; y = hn@W2
    gemm12<<<(N1 + 127) / 128, 512, 0, stream>>>(agg, Bp1, Bp2, rs_in1, rs_out2, b1, y, N1);

    // layer 2 aggregation + fused epilogue: out = relu(rs_in2*segsum(y) + b2)
    agg_final<<<(N2 + 3) / 4, 256, 0, stream>>>((const unsigned int*)y, csr2, cnt_in2,
                                                rs_in2, b2, (float*)d_out, N2);
}

// Round 4
// 365.221 us; speedup vs baseline: 1.2099x; 1.0336x over previous
//
#include <hip/hip_runtime.h>
#include <hip/hip_bf16.h>

#define F1 128
#define F2 256
#define F3 128
#define CAP 64

// bucket geometry: 256 nodes per bucket
#define NB1D 391   // ceil(100000/256) dst1 buckets
#define NB2D 196   // ceil(50000/256)  dst2 buckets
#define NB1S 782   // ceil(200000/256) src1 buckets
#define NB2S 391   // ceil(100000/256) src2 buckets
#define CAPD 4608  // dst-bucket capacity (mean ~4092, sd ~64 -> 8 sigma)
#define CAPS 2432  // src-bucket capacity (mean ~2046, sd ~45 -> 8.5 sigma)
// gcnt layout offsets
#define GD1 0
#define GD2 391
#define GS1 587
#define GS2 1369

typedef __attribute__((ext_vector_type(8))) short bf16x8;
typedef __attribute__((ext_vector_type(4))) float f32x4;
typedef __attribute__((ext_vector_type(4))) unsigned int u32x4;

__device__ inline float bf2f(unsigned short u) {
    return __uint_as_float(((unsigned int)u) << 16);
}
__device__ inline unsigned short f2bf(float f) {
    __hip_bfloat16 b = __float2bfloat16(f);
    return *reinterpret_cast<unsigned short*>(&b);
}
__device__ inline unsigned int pack2(float lo, float hi) {
    return ((unsigned int)f2bf(hi) << 16) | f2bf(lo);
}

// ---------------------------------------------------------------- kernel A (1024 thr)
// block ranges: [0,A1) L1 edge scatter (8192 edges, 8 iters), [A1,A1+A2) L2,
// [+B3) x fp32->bf16 (8192 elems/block), [+64) weight permutes (32 blocks each).
__global__ __launch_bounds__(1024) void scatter_build(
    const int* __restrict__ src1, const int* __restrict__ dst1,
    const int* __restrict__ src2, const int* __restrict__ dst2,
    const float* __restrict__ x, const float* __restrict__ W1,
    const float* __restrict__ W2, int* __restrict__ gcnt,
    unsigned int* __restrict__ bkt_d1, unsigned int* __restrict__ bkt_d2,
    unsigned char* __restrict__ bkt_s1, unsigned char* __restrict__ bkt_s2,
    unsigned int* __restrict__ xn, unsigned short* __restrict__ Bp1,
    unsigned short* __restrict__ Bp2, int E1, int E2, int A1, int A2, int B3) {
    __shared__ int hist[1184];  // >= NB1D + NB1S = 1173
    int b = blockIdx.x, t = threadIdx.x;

    if (b < A1 + A2) {
        const int L1 = (b < A1);
        const int* __restrict__ src = L1 ? src1 : src2;
        const int* __restrict__ dst = L1 ? dst1 : dst2;
        const int E = L1 ? E1 : E2;
        const int NBd = L1 ? NB1D : NB2D;
        const int NBs = L1 ? NB1S : NB2S;
        int* gd = gcnt + (L1 ? GD1 : GD2);
        int* gs = gcnt + (L1 ? GS1 : GS2);
        unsigned int* bd = L1 ? bkt_d1 : bkt_d2;
        unsigned char* bs = L1 ? bkt_s1 : bkt_s2;
        int* hd = hist;
        int* hs = hist + NBd;
        for (int i = t; i < NBd + NBs; i += 1024) hist[i] = 0;
        __syncthreads();
        int e0 = (L1 ? b : b - A1) * 8192;
        // pass 1: local histograms; cache edges in registers for pass 2
        int se[8], de[8];
#pragma unroll
        for (int i = 0; i < 8; ++i) {
            int e = e0 + i * 1024 + t;
            se[i] = -1;
            de[i] = -1;
            if (e < E) {
                int s = src[e], d = dst[e];
                se[i] = s;
                de[i] = d;
                atomicAdd(&hd[d >> 8], 1);
                atomicAdd(&hs[s >> 8], 1);
            }
        }
        __syncthreads();
        // reserve global space; hist becomes cursor (global base)
        for (int i = t; i < NBd; i += 1024) {
            int c = hd[i];
            hd[i] = c ? atomicAdd(&gd[i], c) : 0;
        }
        for (int i = t; i < NBs; i += 1024) {
            int c = hs[i];
            hs[i] = c ? atomicAdd(&gs[i], c) : 0;
        }
        __syncthreads();
        // pass 2: scatter into buckets (runs contiguous per (block,bucket))
#pragma unroll
        for (int i = 0; i < 8; ++i) {
            if (de[i] >= 0) {
                int s = se[i], d = de[i];
                int pd = atomicAdd(&hd[d >> 8], 1);
                if (pd < CAPD)
                    bd[(size_t)(d >> 8) * CAPD + pd] = ((unsigned int)s << 8) | (d & 255);
                int ps = atomicAdd(&hs[s >> 8], 1);
                if (ps < CAPS)
                    bs[(size_t)(s >> 8) * CAPS + ps] = (unsigned char)(s & 255);
            }
        }
    } else if (b < A1 + A2 + B3) {
        // x fp32 -> bf16, 8 elems/thread, exact thread count.
        // Non-temporal loads: x is read exactly once; keep it out of L2 so it
        // doesn't evict partially-filled bucket lines (write-amp reduction).
        size_t tid = (size_t)(b - A1 - A2) * 1024 + t;
        const f32x4* xp = (const f32x4*)x;
        f32x4 a = __builtin_nontemporal_load(xp + tid * 2);
        f32x4 c = __builtin_nontemporal_load(xp + tid * 2 + 1);
        u32x4 o;
        o.x = pack2(a.x, a.y);
        o.y = pack2(a.z, a.w);
        o.z = pack2(c.x, c.y);
        o.w = pack2(c.z, c.w);
        ((u32x4*)xn)[tid] = o;
    } else {
        int w = b - (A1 + A2 + B3);          // 0..63; 32 blocks per weight
        int which = w >> 5;
        const float* W = which ? W2 : W1;
        unsigned short* out = which ? Bp2 : Bp1;
        int N = which ? F3 : F2;
        int idx = (w & 31) * 1024 + t;       // both weights have 32768 elems
        int k = idx / N, n = idx % N;
        unsigned short v = f2bf(W[idx]);
        int kt = k >> 5, q = (k >> 3) & 3, j = k & 7;
        int nt = n >> 4, lane = q * 16 + (n & 15);
        int NT = N >> 4;
        out[(((kt * NT + nt) * 64 + lane) << 3) + j] = v;
    }
}

// ---------------------------------------------------------------- kernel B
// one block per bucket. dst-buckets: padded CSR + cnt_in + rs_in.
// src-buckets: degree histogram -> rs_out.
__global__ __launch_bounds__(256) void bucket_build(
    const int* __restrict__ gcnt,
    const unsigned int* __restrict__ bkt_d1, const unsigned int* __restrict__ bkt_d2,
    const unsigned char* __restrict__ bkt_s1, const unsigned char* __restrict__ bkt_s2,
    int* __restrict__ csr1, int* __restrict__ cnt_in1, float* __restrict__ rs_in1,
    int* __restrict__ csr2, int* __restrict__ cnt_in2, float* __restrict__ rs_in2,
    float* __restrict__ rs_out1, float* __restrict__ rs_out2) {
    __shared__ int hist[256];
    int b = blockIdx.x, t = threadIdx.x;
    hist[t] = 0;
    __syncthreads();

    if (b < NB1D + NB2D) {
        const int L1 = (b < NB1D);
        int bb = L1 ? b : b - NB1D;
        const unsigned int* bkt = L1 ? bkt_d1 : bkt_d2;
        int* csr = L1 ? csr1 : csr2;
        int* cnt_in = L1 ? cnt_in1 : cnt_in2;
        float* rs_in = L1 ? rs_in1 : rs_in2;
        int Nd = L1 ? 100000 : 50000;
        int n = gcnt[(L1 ? GD1 : GD2) + bb];
        if (n > CAPD) n = CAPD;
        size_t base = (size_t)bb * CAPD;
        for (int i = t; i < n; i += 256) {
            unsigned int v = bkt[base + i];
            int d = v & 255, s = (int)(v >> 8);
            int pos = atomicAdd(&hist[d], 1);
            if (pos < CAP) csr[((size_t)(bb * 256 + d)) * CAP + pos] = s;
        }
        __syncthreads();
        int node = bb * 256 + t;
        if (node < Nd) {
            int c = hist[t];
            cnt_in[node] = c < CAP ? c : CAP;
            rs_in[node] = rsqrtf((float)(c < 1 ? 1 : c));
        }
    } else {
        const int L1 = (b < NB1D + NB2D + NB1S);
        int bb = L1 ? b - (NB1D + NB2D) : b - (NB1D + NB2D + NB1S);
        const unsigned char* bkt = L1 ? bkt_s1 : bkt_s2;
        float* rs_out = L1 ? rs_out1 : rs_out2;
        int Ns = L1 ? 200000 : 100000;
        int n = gcnt[(L1 ? GS1 : GS2) + bb];
        if (n > CAPS) n = CAPS;
        size_t base = (size_t)bb * CAPS;
        for (int i = t; i < n; i += 256) atomicAdd(&hist[bkt[base + i]], 1);
        __syncthreads();
        int node = bb * 256 + t;
        if (node < Ns) rs_out[node] = rsqrtf((float)(hist[t] < 1 ? 1 : hist[t]));
    }
}

// ---------------------------------------------------------------- gather aggregation
// F=128 bf16 rows, one wave per dst row. eg = lane>>4 picks one of 4 edges per
// group, fs = lane&15 picks a 16B feature slot.
// Latency-chain fix (round 3): preload ALL edges once (lane l loads csr[base+l]
// and rs_src of it -> one coalesced load + one gather per wave), then per
// iteration get (s,c) via __shfl (VALU) instead of chained memory loads.
// 8 edges/iteration -> two independent row-gathers in flight (2x MLP).
// With step 8 and len<=64, shfl indices <= 63 (no wrap). Lanes >= len hold
// s=0, so dead gathers hit the cached row 0 and are masked by c=0.
__global__ __launch_bounds__(256) void agg128_kernel(
    const unsigned int* __restrict__ X, const int* __restrict__ csr,
    const int* __restrict__ cnt, const float* __restrict__ rs_src,
    unsigned int* __restrict__ out, int ndst) {
    int wave = (int)((blockIdx.x * blockDim.x + threadIdx.x) >> 6);
    int lane = threadIdx.x & 63;
    if (wave >= ndst) return;
    size_t base = (size_t)wave * CAP;
    int len = cnt[wave];
    int sl = 0;
    float clv = 0.f;
    if (lane < len) {
        sl = csr[base + lane];
        clv = rs_src[sl];
    }
    int eg = lane >> 4, fs = lane & 15;
    float acc[8];
#pragma unroll
    for (int i = 0; i < 8; ++i) acc[i] = 0.f;
    for (int j = 0; j < len; j += 8) {
        int jA = j + eg, jB = j + 4 + eg;
        int sA = __shfl(sl, jA);
        int sB = __shfl(sl, jB);
        float cA = __shfl(clv, jA);
        float cB = __shfl(clv, jB);
        u32x4 uA = *(const u32x4*)(X + (size_t)sA * 64 + (fs << 2));
        u32x4 uB = *(const u32x4*)(X + (size_t)sB * 64 + (fs << 2));
        acc[0] = fmaf(cA, bf2f(uA.x & 0xffff), acc[0]);
        acc[1] = fmaf(cA, bf2f(uA.x >> 16), acc[1]);
        acc[2] = fmaf(cA, bf2f(uA.y & 0xffff), acc[2]);
        acc[3] = fmaf(cA, bf2f(uA.y >> 16), acc[3]);
        acc[4] = fmaf(cA, bf2f(uA.z & 0xffff), acc[4]);
        acc[5] = fmaf(cA, bf2f(uA.z >> 16), acc[5]);
        acc[6] = fmaf(cA, bf2f(uA.w & 0xffff), acc[6]);
        acc[7] = fmaf(cA, bf2f(uA.w >> 16), acc[7]);
        acc[0] = fmaf(cB, bf2f(uB.x & 0xffff), acc[0]);
        acc[1] = fmaf(cB, bf2f(uB.x >> 16), acc[1]);
        acc[2] = fmaf(cB, bf2f(uB.y & 0xffff), acc[2]);
        acc[3] = fmaf(cB, bf2f(uB.y >> 16), acc[3]);
        acc[4] = fmaf(cB, bf2f(uB.z & 0xffff), acc[4]);
        acc[5] = fmaf(cB, bf2f(uB.z >> 16), acc[5]);
        acc[6] = fmaf(cB, bf2f(uB.w & 0xffff), acc[6]);
        acc[7] = fmaf(cB, bf2f(uB.w >> 16), acc[7]);
    }
#pragma unroll
    for (int i = 0; i < 8; ++i) {
        acc[i] += __shfl_xor(acc[i], 16);
        acc[i] += __shfl_xor(acc[i], 32);
    }
    if (eg == 0) {
        u32x4 o;
        o.x = pack2(acc[0], acc[1]);
        o.y = pack2(acc[2], acc[3]);
        o.z = pack2(acc[4], acc[5]);
        o.w = pack2(acc[6], acc[7]);
        *((u32x4*)(out + (size_t)wave * 64) + fs) = o;
    }
}

// ---------------------------------------------------------------- fused two-stage GEMM
// 512 threads = 8 waves x 16 rows = 128-row tile.
// B matrices staged in LDS (they are shared by every wave of every block):
//   phase 0: coop-copy Bp1 (64 KB) global->LDS
//   stage 1: tmp = relu(rs1[m]*(A@W1)+b1)*rs2[m]   (B from LDS, conflict-free b128)
//   phase 2: coop-copy Bp2 (64 KB) over the same LDS region
//   stage 2: Y = tmp @ W2                           (B from LDS)
// LDS total 130 KB -> 1 block/CU.
__global__ __launch_bounds__(512) void gemm12(
    const unsigned short* __restrict__ A,    // agg [M,128] bf16
    const unsigned short* __restrict__ Bp1,  // W1 fragments (K=128,N=256)
    const unsigned short* __restrict__ Bp2,  // W2 fragments (K=256,N=128)
    const float* __restrict__ rs1, const float* __restrict__ rs2,
    const float* __restrict__ bias1,
    unsigned short* __restrict__ Y, int M) {
    __shared__ unsigned short Bs[32768];      // 64 KB, holds Bp1 then Bp2
    __shared__ unsigned short tmp[128][264];  // +8 pad, 67.6 KB
    int lane = threadIdx.x & 63, wid = threadIdx.x >> 6;
    int t = threadIdx.x;
    int row0 = blockIdx.x * 128 + wid * 16;
    int q = lane >> 4, col = lane & 15;

    // ---- phase 0: Bp1 -> LDS (4096 uint4 / 512 threads = 8 iters)
#pragma unroll
    for (int i = 0; i < 8; ++i)
        ((u32x4*)Bs)[i * 512 + t] = ((const u32x4*)Bp1)[i * 512 + t];
    __syncthreads();

    // ---- stage 1: 16 rows x 256 cols per wave
    int mload = row0 + col;
    if (mload > M - 1) mload = M - 1;
    const unsigned short* Arow = A + (size_t)mload * F1 + q * 8;
    f32x4 acc[16];
#pragma unroll
    for (int i = 0; i < 16; ++i) acc[i] = (f32x4){0.f, 0.f, 0.f, 0.f};
#pragma unroll
    for (int kt = 0; kt < 4; ++kt) {
        bf16x8 a = *(const bf16x8*)(Arow + kt * 32);
#pragma unroll
        for (int nt = 0; nt < 16; ++nt) {
            bf16x8 b = *(const bf16x8*)(Bs + (((kt * 16 + nt) * 64 + lane) << 3));
            acc[nt] = __builtin_amdgcn_mfma_f32_16x16x32_bf16(a, b, acc[nt], 0, 0, 0);
        }
    }
#pragma unroll
    for (int r = 0; r < 4; ++r) {
        int lrow = wid * 16 + q * 4 + r;
        int m = row0 + q * 4 + r;
        int mc = m < M ? m : M - 1;
        float s1 = rs1[mc], s2 = rs2[mc];
#pragma unroll
        for (int nt = 0; nt < 16; ++nt) {
            float v = fmaxf(fmaf(acc[nt][r], s1, bias1[nt * 16 + col]), 0.f) * s2;
            tmp[lrow][nt * 16 + col] = f2bf(v);
        }
    }
    __syncthreads();

    // ---- phase 2: Bp2 -> LDS (overwrite Bp1 region)
#pragma unroll
    for (int i = 0; i < 8; ++i)
        ((u32x4*)Bs)[i * 512 + t] = ((const u32x4*)Bp2)[i * 512 + t];
    __syncthreads();

    // ---- stage 2: same 16 rows x 128 cols, K=256 from tmp
    f32x4 acc2[8];
#pragma unroll
    for (int i = 0; i < 8; ++i) acc2[i] = (f32x4){0.f, 0.f, 0.f, 0.f};
    const unsigned short* trow = &tmp[wid * 16 + col][q * 8];
#pragma unroll
    for (int kt = 0; kt < 8; ++kt) {
        bf16x8 a = *(const bf16x8*)(trow + kt * 32);
#pragma unroll
        for (int nt = 0; nt < 8; ++nt) {
            bf16x8 b = *(const bf16x8*)(Bs + (((kt * 8 + nt) * 64 + lane) << 3));
            acc2[nt] = __builtin_amdgcn_mfma_f32_16x16x32_bf16(a, b, acc2[nt], 0, 0, 0);
        }
    }
#pragma unroll
    for (int r = 0; r < 4; ++r) {
        int m = row0 + q * 4 + r;
        if (m >= M) continue;
#pragma unroll
        for (int nt = 0; nt < 8; ++nt)
            Y[(size_t)m * F3 + nt * 16 + col] = f2bf(acc2[nt][r]);
    }
}

// ---------------------------------------------------------------- final aggregation
// gather y rows (128 bf16), sum, out = relu(rs_in2[d]*sum + b2) -> fp32
// Same preload+shfl+2xMLP structure as agg128_kernel (mask instead of norm).
__global__ __launch_bounds__(256) void agg_final(
    const unsigned int* __restrict__ Yv, const int* __restrict__ csr,
    const int* __restrict__ cnt, const float* __restrict__ rs_dst,
    const float* __restrict__ b2, float* __restrict__ out, int ndst) {
    int wave = (int)((blockIdx.x * blockDim.x + threadIdx.x) >> 6);
    int lane = threadIdx.x & 63;
    if (wave >= ndst) return;
    size_t base = (size_t)wave * CAP;
    int len = cnt[wave];
    int sl = 0;
    float clv = 0.f;
    if (lane < len) {
        sl = csr[base + lane];
        clv = 1.f;
    }
    int eg = lane >> 4, fs = lane & 15;
    float acc[8];
#pragma unroll
    for (int i = 0; i < 8; ++i) acc[i] = 0.f;
    for (int j = 0; j < len; j += 8) {
        int jA = j + eg, jB = j + 4 + eg;
        int sA = __shfl(sl, jA);
        int sB = __shfl(sl, jB);
        float cA = __shfl(clv, jA);
        float cB = __shfl(clv, jB);
        u32x4 uA = *(const u32x4*)(Yv + (size_t)sA * 64 + (fs << 2));
        u32x4 uB = *(const u32x4*)(Yv + (size_t)sB * 64 + (fs << 2));
        acc[0] = fmaf(cA, bf2f(uA.x & 0xffff), acc[0]);
        acc[1] = fmaf(cA, bf2f(uA.x >> 16), acc[1]);
        acc[2] = fmaf(cA, bf2f(uA.y & 0xffff), acc[2]);
        acc[3] = fmaf(cA, bf2f(uA.y >> 16), acc[3]);
        acc[4] = fmaf(cA, bf2f(uA.z & 0xffff), acc[4]);
        acc[5] = fmaf(cA, bf2f(uA.z >> 16), acc[5]);
        acc[6] = fmaf(cA, bf2f(uA.w & 0xffff), acc[6]);
        acc[7] = fmaf(cA, bf2f(uA.w >> 16), acc[7]);
        acc[0] = fmaf(cB, bf2f(uB.x & 0xffff), acc[0]);
        acc[1] = fmaf(cB, bf2f(uB.x >> 16), acc[1]);
        acc[2] = fmaf(cB, bf2f(uB.y & 0xffff), acc[2]);
        acc[3] = fmaf(cB, bf2f(uB.y >> 16), acc[3]);
        acc[4] = fmaf(cB, bf2f(uB.z & 0xffff), acc[4]);
        acc[5] = fmaf(cB, bf2f(uB.z >> 16), acc[5]);
        acc[6] = fmaf(cB, bf2f(uB.w & 0xffff), acc[6]);
        acc[7] = fmaf(cB, bf2f(uB.w >> 16), acc[7]);
    }
#pragma unroll
    for (int i = 0; i < 8; ++i) {
        acc[i] += __shfl_xor(acc[i], 16);
        acc[i] += __shfl_xor(acc[i], 32);
    }
    if (eg < 2) {
        float sc = rs_dst[wave];
        f32x4 bias = ((const f32x4*)b2)[(fs << 1) | eg];
        // static-index selection (no runtime-indexed register array)
        float v0 = eg ? acc[4] : acc[0];
        float v1 = eg ? acc[5] : acc[1];
        float v2 = eg ? acc[6] : acc[2];
        float v3 = eg ? acc[7] : acc[3];
        f32x4 o;
        o.x = fmaxf(fmaf(v0, sc, bias.x), 0.f);
        o.y = fmaxf(fmaf(v1, sc, bias.y), 0.f);
        o.z = fmaxf(fmaf(v2, sc, bias.z), 0.f);
        o.w = fmaxf(fmaf(v3, sc, bias.w), 0.f);
        __builtin_nontemporal_store(o, (f32x4*)out + (size_t)wave * 32 + (fs << 1) + eg);
    }
}

extern "C" void kernel_launch(void* const* d_in, const int* in_sizes, int n_in,
                              void* d_out, int out_size, void* d_ws, size_t ws_size,
                              hipStream_t stream) {
    const float* x  = (const float*)d_in[0];
    const float* W1 = (const float*)d_in[1];
    const float* b1 = (const float*)d_in[2];
    const float* W2 = (const float*)d_in[3];
    const float* b2 = (const float*)d_in[4];
    const int* src1 = (const int*)d_in[5];
    const int* dst1 = (const int*)d_in[6];
    const int* src2 = (const int*)d_in[7];
    const int* dst2 = (const int*)d_in[8];
    const int E1 = in_sizes[5], E2 = in_sizes[7];
    const int N0 = in_sizes[0] / F1;  // 200000
    const int N1 = 100000, N2 = 50000;

    // ---- workspace layout (all segment sizes multiples of 16 B)
    char* p = (char*)d_ws;
    int* gcnt = (int*)p; p += 2048 * 4;                          // 1760 used
    float* rs_out1 = (float*)p; p += (size_t)N0 * 4;
    float* rs_in1  = (float*)p; p += (size_t)N1 * 4;
    float* rs_out2 = (float*)p; p += (size_t)N1 * 4;
    float* rs_in2  = (float*)p; p += (size_t)N2 * 4;
    int* cnt_in1 = (int*)p; p += (size_t)N1 * 4;
    int* cnt_in2 = (int*)p; p += (size_t)N2 * 4;
    unsigned int* bkt_d1 = (unsigned int*)p; p += (size_t)NB1D * CAPD * 4;  // 7.2 MB
    unsigned int* bkt_d2 = (unsigned int*)p; p += (size_t)NB2D * CAPD * 4;  // 3.6 MB
    unsigned char* bkt_s1 = (unsigned char*)p; p += (size_t)NB1S * CAPS;    // 1.9 MB
    unsigned char* bkt_s2 = (unsigned char*)p; p += (size_t)NB2S * CAPS;    // 1.0 MB
    int* csr1 = (int*)p; p += (size_t)N1 * CAP * 4;              // 25.6 MB
    int* csr2 = (int*)p; p += (size_t)N2 * CAP * 4;              // 12.8 MB
    unsigned short* Bp1 = (unsigned short*)p; p += (size_t)F1 * F2 * 2;
    unsigned short* Bp2 = (unsigned short*)p; p += (size_t)F2 * F3 * 2;
    unsigned short* xn  = (unsigned short*)p; p += (size_t)N0 * F1 * 2;  // 51.2 MB
    unsigned short* agg = (unsigned short*)p; p += (size_t)N1 * F1 * 2;  // 25.6 MB
    // y aliases xn: xn (25.6M elems) dead after agg128; y (N1*F3=12.8M elems) born at gemm12
    unsigned short* y = xn;

    (void)hipMemsetAsync(gcnt, 0, 2048 * 4, stream);

    // kernel A: bucket scatter (both layers) + x->bf16 + weight permutes
    int A1 = (E1 + 8191) / 8192;
    int A2 = (E2 + 8191) / 8192;
    int B3 = N0 * F1 / 8 / 1024;  // exact: 3125
    scatter_build<<<A1 + A2 + B3 + 64, 1024, 0, stream>>>(
        src1, dst1, src2, dst2, x, W1, W2, gcnt,
        bkt_d1, bkt_d2, bkt_s1, bkt_s2,
        (unsigned int*)xn, Bp1, Bp2, E1, E2, A1, A2, B3);

    // kernel B: per-bucket CSR + degree norms
    bucket_build<<<NB1D + NB2D + NB1S + NB2S, 256, 0, stream>>>(
        gcnt, bkt_d1, bkt_d2, bkt_s1, bkt_s2,
        csr1, cnt_in1, rs_in1, csr2, cnt_in2, rs_in2, rs_out1, rs_out2);

    // layer 1 aggregation (per-edge src norm)
    agg128_kernel<<<(N1 + 3) / 4, 256, 0, stream>>>((const unsigned int*)xn, csr1,
                                                    cnt_in1, rs_out1,
                                                    (unsigned int*)agg, N1);

    // fused: hn = relu(rs_in1*(agg@W1)+b1)*rs_out2 ; y = hn@W2
    gemm12<<<(N1 + 127) / 128, 512, 0, stream>>>(agg, Bp1, Bp2, rs_in1, rs_out2, b1, y, N1);

    // layer 2 aggregation + fused epilogue: out = relu(rs_in2*segsum(y) + b2)
    agg_final<<<(N2 + 3) / 4, 256, 0, stream>>>((const unsigned int*)y, csr2, cnt_in2,
                                                rs_in2, b2, (float*)d_out, N2);
}

// Round 5
// 363.010 us; speedup vs baseline: 1.2172x; 1.0061x over previous
//
#include <hip/hip_runtime.h>
#include <hip/hip_bf16.h>

#define F1 128
#define F2 256
#define F3 128
#define CAP 64

// bucket geometry: 256 nodes per bucket
#define NB1D 391   // ceil(100000/256) dst1 buckets
#define NB2D 196   // ceil(50000/256)  dst2 buckets
#define NB1S 782   // ceil(200000/256) src1 buckets
#define NB2S 391   // ceil(100000/256) src2 buckets
#define CAPD 4608  // dst-bucket capacity (mean ~4092, sd ~64 -> 8 sigma)
#define CAPS 2432  // src-bucket capacity (mean ~2046, sd ~45 -> 8.5 sigma)
// gcnt layout offsets
#define GD1 0
#define GD2 391
#define GS1 587
#define GS2 1369

typedef __attribute__((ext_vector_type(8))) short bf16x8;
typedef __attribute__((ext_vector_type(4))) float f32x4;
typedef __attribute__((ext_vector_type(4))) unsigned int u32x4;

__device__ inline float bf2f(unsigned short u) {
    return __uint_as_float(((unsigned int)u) << 16);
}
__device__ inline unsigned short f2bf(float f) {
    __hip_bfloat16 b = __float2bfloat16(f);
    return *reinterpret_cast<unsigned short*>(&b);
}
__device__ inline unsigned int pack2(float lo, float hi) {
    return ((unsigned int)f2bf(hi) << 16) | f2bf(lo);
}

// accumulate one gathered row (u) scaled by c into acc[0..7]
#define ACC_ROW(u, c)                                   \
    acc[0] = fmaf(c, bf2f(u.x & 0xffff), acc[0]);       \
    acc[1] = fmaf(c, bf2f(u.x >> 16), acc[1]);          \
    acc[2] = fmaf(c, bf2f(u.y & 0xffff), acc[2]);       \
    acc[3] = fmaf(c, bf2f(u.y >> 16), acc[3]);          \
    acc[4] = fmaf(c, bf2f(u.z & 0xffff), acc[4]);       \
    acc[5] = fmaf(c, bf2f(u.z >> 16), acc[5]);          \
    acc[6] = fmaf(c, bf2f(u.w & 0xffff), acc[6]);       \
    acc[7] = fmaf(c, bf2f(u.w >> 16), acc[7]);

// ---------------------------------------------------------------- kernel A (1024 thr)
// block ranges: [0,A1) L1 edge scatter (8192 edges, 8 iters), [A1,A1+A2) L2,
// [+B3) x fp32->bf16 (8192 elems/block), [+64) weight permutes (32 blocks each).
__global__ __launch_bounds__(1024) void scatter_build(
    const int* __restrict__ src1, const int* __restrict__ dst1,
    const int* __restrict__ src2, const int* __restrict__ dst2,
    const float* __restrict__ x, const float* __restrict__ W1,
    const float* __restrict__ W2, int* __restrict__ gcnt,
    unsigned int* __restrict__ bkt_d1, unsigned int* __restrict__ bkt_d2,
    unsigned char* __restrict__ bkt_s1, unsigned char* __restrict__ bkt_s2,
    unsigned int* __restrict__ xn, unsigned short* __restrict__ Bp1,
    unsigned short* __restrict__ Bp2, int E1, int E2, int A1, int A2, int B3) {
    __shared__ int hist[1184];  // >= NB1D + NB1S = 1173
    int b = blockIdx.x, t = threadIdx.x;

    if (b < A1 + A2) {
        const int L1 = (b < A1);
        const int* __restrict__ src = L1 ? src1 : src2;
        const int* __restrict__ dst = L1 ? dst1 : dst2;
        const int E = L1 ? E1 : E2;
        const int NBd = L1 ? NB1D : NB2D;
        const int NBs = L1 ? NB1S : NB2S;
        int* gd = gcnt + (L1 ? GD1 : GD2);
        int* gs = gcnt + (L1 ? GS1 : GS2);
        unsigned int* bd = L1 ? bkt_d1 : bkt_d2;
        unsigned char* bs = L1 ? bkt_s1 : bkt_s2;
        int* hd = hist;
        int* hs = hist + NBd;
        for (int i = t; i < NBd + NBs; i += 1024) hist[i] = 0;
        __syncthreads();
        int e0 = (L1 ? b : b - A1) * 8192;
        // pass 1: local histograms; cache edges in registers for pass 2
        int se[8], de[8];
#pragma unroll
        for (int i = 0; i < 8; ++i) {
            int e = e0 + i * 1024 + t;
            se[i] = -1;
            de[i] = -1;
            if (e < E) {
                int s = src[e], d = dst[e];
                se[i] = s;
                de[i] = d;
                atomicAdd(&hd[d >> 8], 1);
                atomicAdd(&hs[s >> 8], 1);
            }
        }
        __syncthreads();
        // reserve global space; hist becomes cursor (global base)
        for (int i = t; i < NBd; i += 1024) {
            int c = hd[i];
            hd[i] = c ? atomicAdd(&gd[i], c) : 0;
        }
        for (int i = t; i < NBs; i += 1024) {
            int c = hs[i];
            hs[i] = c ? atomicAdd(&gs[i], c) : 0;
        }
        __syncthreads();
        // pass 2: scatter into buckets (runs contiguous per (block,bucket))
#pragma unroll
        for (int i = 0; i < 8; ++i) {
            if (de[i] >= 0) {
                int s = se[i], d = de[i];
                int pd = atomicAdd(&hd[d >> 8], 1);
                if (pd < CAPD)
                    bd[(size_t)(d >> 8) * CAPD + pd] = ((unsigned int)s << 8) | (d & 255);
                int ps = atomicAdd(&hs[s >> 8], 1);
                if (ps < CAPS)
                    bs[(size_t)(s >> 8) * CAPS + ps] = (unsigned char)(s & 255);
            }
        }
    } else if (b < A1 + A2 + B3) {
        // x fp32 -> bf16, 8 elems/thread, exact thread count.
        // Non-temporal loads: x is read exactly once; keep it out of L2 so it
        // doesn't evict partially-filled bucket lines (write-amp reduction).
        size_t tid = (size_t)(b - A1 - A2) * 1024 + t;
        const f32x4* xp = (const f32x4*)x;
        f32x4 a = __builtin_nontemporal_load(xp + tid * 2);
        f32x4 c = __builtin_nontemporal_load(xp + tid * 2 + 1);
        u32x4 o;
        o.x = pack2(a.x, a.y);
        o.y = pack2(a.z, a.w);
        o.z = pack2(c.x, c.y);
        o.w = pack2(c.z, c.w);
        ((u32x4*)xn)[tid] = o;
    } else {
        int w = b - (A1 + A2 + B3);          // 0..63; 32 blocks per weight
        int which = w >> 5;
        const float* W = which ? W2 : W1;
        unsigned short* out = which ? Bp2 : Bp1;
        int N = which ? F3 : F2;
        int idx = (w & 31) * 1024 + t;       // both weights have 32768 elems
        int k = idx / N, n = idx % N;
        unsigned short v = f2bf(W[idx]);
        int kt = k >> 5, q = (k >> 3) & 3, j = k & 7;
        int nt = n >> 4, lane = q * 16 + (n & 15);
        int NT = N >> 4;
        out[(((kt * NT + nt) * 64 + lane) << 3) + j] = v;
    }
}

// ---------------------------------------------------------------- kernel B
// one block per bucket. dst-buckets: padded CSR + cnt_in + rs_in.
// src-buckets: degree histogram -> rs_out.
__global__ __launch_bounds__(256) void bucket_build(
    const int* __restrict__ gcnt,
    const unsigned int* __restrict__ bkt_d1, const unsigned int* __restrict__ bkt_d2,
    const unsigned char* __restrict__ bkt_s1, const unsigned char* __restrict__ bkt_s2,
    int* __restrict__ csr1, int* __restrict__ cnt_in1, float* __restrict__ rs_in1,
    int* __restrict__ csr2, int* __restrict__ cnt_in2, float* __restrict__ rs_in2,
    float* __restrict__ rs_out1, float* __restrict__ rs_out2) {
    __shared__ int hist[256];
    int b = blockIdx.x, t = threadIdx.x;
    hist[t] = 0;
    __syncthreads();

    if (b < NB1D + NB2D) {
        const int L1 = (b < NB1D);
        int bb = L1 ? b : b - NB1D;
        const unsigned int* bkt = L1 ? bkt_d1 : bkt_d2;
        int* csr = L1 ? csr1 : csr2;
        int* cnt_in = L1 ? cnt_in1 : cnt_in2;
        float* rs_in = L1 ? rs_in1 : rs_in2;
        int Nd = L1 ? 100000 : 50000;
        int n = gcnt[(L1 ? GD1 : GD2) + bb];
        if (n > CAPD) n = CAPD;
        size_t base = (size_t)bb * CAPD;
        for (int i = t; i < n; i += 256) {
            unsigned int v = bkt[base + i];
            int d = v & 255, s = (int)(v >> 8);
            int pos = atomicAdd(&hist[d], 1);
            if (pos < CAP) csr[((size_t)(bb * 256 + d)) * CAP + pos] = s;
        }
        __syncthreads();
        int node = bb * 256 + t;
        if (node < Nd) {
            int c = hist[t];
            cnt_in[node] = c < CAP ? c : CAP;
            rs_in[node] = rsqrtf((float)(c < 1 ? 1 : c));
        }
    } else {
        const int L1 = (b < NB1D + NB2D + NB1S);
        int bb = L1 ? b - (NB1D + NB2D) : b - (NB1D + NB2D + NB1S);
        const unsigned char* bkt = L1 ? bkt_s1 : bkt_s2;
        float* rs_out = L1 ? rs_out1 : rs_out2;
        int Ns = L1 ? 200000 : 100000;
        int n = gcnt[(L1 ? GS1 : GS2) + bb];
        if (n > CAPS) n = CAPS;
        size_t base = (size_t)bb * CAPS;
        for (int i = t; i < n; i += 256) atomicAdd(&hist[bkt[base + i]], 1);
        __syncthreads();
        int node = bb * 256 + t;
        if (node < Ns) rs_out[node] = rsqrtf((float)(hist[t] < 1 ? 1 : hist[t]));
    }
}

// ---------------------------------------------------------------- gather aggregation
// F=128 bf16 rows, one wave per dst row. eg = lane>>4 picks one of 4 edges per
// group, fs = lane&15 picks a 16B feature slot.
// Round 4: 16 edges/iteration = 4 independent u32x4 row-gathers issued
// back-to-back before any consumption. Mean in-degree is 16 -> typical row is
// ONE load-batch (no loop-carried vmcnt drain). Edge ids + norms preloaded
// once (coalesced) and distributed per iteration via __shfl (VALU-only).
// Max shfl index = 48+12+3 = 63 (len<=64): no wrap. Lanes >= len hold s=0 ->
// dead gathers hit cached row 0 and are masked by c=0.
__global__ __launch_bounds__(256) void agg128_kernel(
    const unsigned int* __restrict__ X, const int* __restrict__ csr,
    const int* __restrict__ cnt, const float* __restrict__ rs_src,
    unsigned int* __restrict__ out, int ndst) {
    int wave = (int)((blockIdx.x * blockDim.x + threadIdx.x) >> 6);
    int lane = threadIdx.x & 63;
    if (wave >= ndst) return;
    size_t base = (size_t)wave * CAP;
    int len = cnt[wave];
    int sl = 0;
    float clv = 0.f;
    if (lane < len) {
        sl = csr[base + lane];
        clv = rs_src[sl];
    }
    int eg = lane >> 4, fs = lane & 15;
    float acc[8];
#pragma unroll
    for (int i = 0; i < 8; ++i) acc[i] = 0.f;
    for (int j = 0; j < len; j += 16) {
        int jA = j + eg, jB = j + 4 + eg, jC = j + 8 + eg, jD = j + 12 + eg;
        int sA = __shfl(sl, jA);
        int sB = __shfl(sl, jB);
        int sC = __shfl(sl, jC);
        int sD = __shfl(sl, jD);
        float cA = __shfl(clv, jA);
        float cB = __shfl(clv, jB);
        float cC = __shfl(clv, jC);
        float cD = __shfl(clv, jD);
        u32x4 uA = *(const u32x4*)(X + (size_t)sA * 64 + (fs << 2));
        u32x4 uB = *(const u32x4*)(X + (size_t)sB * 64 + (fs << 2));
        u32x4 uC = *(const u32x4*)(X + (size_t)sC * 64 + (fs << 2));
        u32x4 uD = *(const u32x4*)(X + (size_t)sD * 64 + (fs << 2));
        ACC_ROW(uA, cA)
        ACC_ROW(uB, cB)
        ACC_ROW(uC, cC)
        ACC_ROW(uD, cD)
    }
#pragma unroll
    for (int i = 0; i < 8; ++i) {
        acc[i] += __shfl_xor(acc[i], 16);
        acc[i] += __shfl_xor(acc[i], 32);
    }
    if (eg == 0) {
        u32x4 o;
        o.x = pack2(acc[0], acc[1]);
        o.y = pack2(acc[2], acc[3]);
        o.z = pack2(acc[4], acc[5]);
        o.w = pack2(acc[6], acc[7]);
        *((u32x4*)(out + (size_t)wave * 64) + fs) = o;
    }
}

// ---------------------------------------------------------------- fused two-stage GEMM
// 512 threads = 8 waves x 16 rows = 128-row tile.
// B matrices staged in LDS (they are shared by every wave of every block):
//   phase 0: coop-copy Bp1 (64 KB) global->LDS
//   stage 1: tmp = relu(rs1[m]*(A@W1)+b1)*rs2[m]   (B from LDS, conflict-free b128)
//   phase 2: coop-copy Bp2 (64 KB) over the same LDS region
//   stage 2: Y = tmp @ W2                           (B from LDS)
// LDS total 130 KB -> 1 block/CU.
__global__ __launch_bounds__(512) void gemm12(
    const unsigned short* __restrict__ A,    // agg [M,128] bf16
    const unsigned short* __restrict__ Bp1,  // W1 fragments (K=128,N=256)
    const unsigned short* __restrict__ Bp2,  // W2 fragments (K=256,N=128)
    const float* __restrict__ rs1, const float* __restrict__ rs2,
    const float* __restrict__ bias1,
    unsigned short* __restrict__ Y, int M) {
    __shared__ unsigned short Bs[32768];      // 64 KB, holds Bp1 then Bp2
    __shared__ unsigned short tmp[128][264];  // +8 pad, 67.6 KB
    int lane = threadIdx.x & 63, wid = threadIdx.x >> 6;
    int t = threadIdx.x;
    int row0 = blockIdx.x * 128 + wid * 16;
    int q = lane >> 4, col = lane & 15;

    // ---- phase 0: Bp1 -> LDS (4096 uint4 / 512 threads = 8 iters)
#pragma unroll
    for (int i = 0; i < 8; ++i)
        ((u32x4*)Bs)[i * 512 + t] = ((const u32x4*)Bp1)[i * 512 + t];
    __syncthreads();

    // ---- stage 1: 16 rows x 256 cols per wave
    int mload = row0 + col;
    if (mload > M - 1) mload = M - 1;
    const unsigned short* Arow = A + (size_t)mload * F1 + q * 8;
    f32x4 acc[16];
#pragma unroll
    for (int i = 0; i < 16; ++i) acc[i] = (f32x4){0.f, 0.f, 0.f, 0.f};
#pragma unroll
    for (int kt = 0; kt < 4; ++kt) {
        bf16x8 a = *(const bf16x8*)(Arow + kt * 32);
#pragma unroll
        for (int nt = 0; nt < 16; ++nt) {
            bf16x8 b = *(const bf16x8*)(Bs + (((kt * 16 + nt) * 64 + lane) << 3));
            acc[nt] = __builtin_amdgcn_mfma_f32_16x16x32_bf16(a, b, acc[nt], 0, 0, 0);
        }
    }
#pragma unroll
    for (int r = 0; r < 4; ++r) {
        int lrow = wid * 16 + q * 4 + r;
        int m = row0 + q * 4 + r;
        int mc = m < M ? m : M - 1;
        float s1 = rs1[mc], s2 = rs2[mc];
#pragma unroll
        for (int nt = 0; nt < 16; ++nt) {
            float v = fmaxf(fmaf(acc[nt][r], s1, bias1[nt * 16 + col]), 0.f) * s2;
            tmp[lrow][nt * 16 + col] = f2bf(v);
        }
    }
    __syncthreads();

    // ---- phase 2: Bp2 -> LDS (overwrite Bp1 region)
#pragma unroll
    for (int i = 0; i < 8; ++i)
        ((u32x4*)Bs)[i * 512 + t] = ((const u32x4*)Bp2)[i * 512 + t];
    __syncthreads();

    // ---- stage 2: same 16 rows x 128 cols, K=256 from tmp
    f32x4 acc2[8];
#pragma unroll
    for (int i = 0; i < 8; ++i) acc2[i] = (f32x4){0.f, 0.f, 0.f, 0.f};
    const unsigned short* trow = &tmp[wid * 16 + col][q * 8];
#pragma unroll
    for (int kt = 0; kt < 8; ++kt) {
        bf16x8 a = *(const bf16x8*)(trow + kt * 32);
#pragma unroll
        for (int nt = 0; nt < 8; ++nt) {
            bf16x8 b = *(const bf16x8*)(Bs + (((kt * 8 + nt) * 64 + lane) << 3));
            acc2[nt] = __builtin_amdgcn_mfma_f32_16x16x32_bf16(a, b, acc2[nt], 0, 0, 0);
        }
    }
#pragma unroll
    for (int r = 0; r < 4; ++r) {
        int m = row0 + q * 4 + r;
        if (m >= M) continue;
#pragma unroll
        for (int nt = 0; nt < 8; ++nt)
            Y[(size_t)m * F3 + nt * 16 + col] = f2bf(acc2[nt][r]);
    }
}

// ---------------------------------------------------------------- final aggregation
// gather y rows (128 bf16), sum, out = relu(rs_in2[d]*sum + b2) -> fp32
// Same preload+shfl structure as agg128_kernel, 16 edges/iteration.
__global__ __launch_bounds__(256) void agg_final(
    const unsigned int* __restrict__ Yv, const int* __restrict__ csr,
    const int* __restrict__ cnt, const float* __restrict__ rs_dst,
    const float* __restrict__ b2, float* __restrict__ out, int ndst) {
    int wave = (int)((blockIdx.x * blockDim.x + threadIdx.x) >> 6);
    int lane = threadIdx.x & 63;
    if (wave >= ndst) return;
    size_t base = (size_t)wave * CAP;
    int len = cnt[wave];
    int sl = 0;
    float clv = 0.f;
    if (lane < len) {
        sl = csr[base + lane];
        clv = 1.f;
    }
    int eg = lane >> 4, fs = lane & 15;
    float acc[8];
#pragma unroll
    for (int i = 0; i < 8; ++i) acc[i] = 0.f;
    for (int j = 0; j < len; j += 16) {
        int jA = j + eg, jB = j + 4 + eg, jC = j + 8 + eg, jD = j + 12 + eg;
        int sA = __shfl(sl, jA);
        int sB = __shfl(sl, jB);
        int sC = __shfl(sl, jC);
        int sD = __shfl(sl, jD);
        float cA = __shfl(clv, jA);
        float cB = __shfl(clv, jB);
        float cC = __shfl(clv, jC);
        float cD = __shfl(clv, jD);
        u32x4 uA = *(const u32x4*)(Yv + (size_t)sA * 64 + (fs << 2));
        u32x4 uB = *(const u32x4*)(Yv + (size_t)sB * 64 + (fs << 2));
        u32x4 uC = *(const u32x4*)(Yv + (size_t)sC * 64 + (fs << 2));
        u32x4 uD = *(const u32x4*)(Yv + (size_t)sD * 64 + (fs << 2));
        ACC_ROW(uA, cA)
        ACC_ROW(uB, cB)
        ACC_ROW(uC, cC)
        ACC_ROW(uD, cD)
    }
#pragma unroll
    for (int i = 0; i < 8; ++i) {
        acc[i] += __shfl_xor(acc[i], 16);
        acc[i] += __shfl_xor(acc[i], 32);
    }
    if (eg < 2) {
        float sc = rs_dst[wave];
        f32x4 bias = ((const f32x4*)b2)[(fs << 1) | eg];
        // static-index selection (no runtime-indexed register array)
        float v0 = eg ? acc[4] : acc[0];
        float v1 = eg ? acc[5] : acc[1];
        float v2 = eg ? acc[6] : acc[2];
        float v3 = eg ? acc[7] : acc[3];
        f32x4 o;
        o.x = fmaxf(fmaf(v0, sc, bias.x), 0.f);
        o.y = fmaxf(fmaf(v1, sc, bias.y), 0.f);
        o.z = fmaxf(fmaf(v2, sc, bias.z), 0.f);
        o.w = fmaxf(fmaf(v3, sc, bias.w), 0.f);
        __builtin_nontemporal_store(o, (f32x4*)out + (size_t)wave * 32 + (fs << 1) + eg);
    }
}

extern "C" void kernel_launch(void* const* d_in, const int* in_sizes, int n_in,
                              void* d_out, int out_size, void* d_ws, size_t ws_size,
                              hipStream_t stream) {
    const float* x  = (const float*)d_in[0];
    const float* W1 = (const float*)d_in[1];
    const float* b1 = (const float*)d_in[2];
    const float* W2 = (const float*)d_in[3];
    const float* b2 = (const float*)d_in[4];
    const int* src1 = (const int*)d_in[5];
    const int* dst1 = (const int*)d_in[6];
    const int* src2 = (const int*)d_in[7];
    const int* dst2 = (const int*)d_in[8];
    const int E1 = in_sizes[5], E2 = in_sizes[7];
    const int N0 = in_sizes[0] / F1;  // 200000
    const int N1 = 100000, N2 = 50000;

    // ---- workspace layout (all segment sizes multiples of 16 B)
    char* p = (char*)d_ws;
    int* gcnt = (int*)p; p += 2048 * 4;                          // 1760 used
    float* rs_out1 = (float*)p; p += (size_t)N0 * 4;
    float* rs_in1  = (float*)p; p += (size_t)N1 * 4;
    float* rs_out2 = (float*)p; p += (size_t)N1 * 4;
    float* rs_in2  = (float*)p; p += (size_t)N2 * 4;
    int* cnt_in1 = (int*)p; p += (size_t)N1 * 4;
    int* cnt_in2 = (int*)p; p += (size_t)N2 * 4;
    unsigned int* bkt_d1 = (unsigned int*)p; p += (size_t)NB1D * CAPD * 4;  // 7.2 MB
    unsigned int* bkt_d2 = (unsigned int*)p; p += (size_t)NB2D * CAPD * 4;  // 3.6 MB
    unsigned char* bkt_s1 = (unsigned char*)p; p += (size_t)NB1S * CAPS;    // 1.9 MB
    unsigned char* bkt_s2 = (unsigned char*)p; p += (size_t)NB2S * CAPS;    // 1.0 MB
    int* csr1 = (int*)p; p += (size_t)N1 * CAP * 4;              // 25.6 MB
    int* csr2 = (int*)p; p += (size_t)N2 * CAP * 4;              // 12.8 MB
    unsigned short* Bp1 = (unsigned short*)p; p += (size_t)F1 * F2 * 2;
    unsigned short* Bp2 = (unsigned short*)p; p += (size_t)F2 * F3 * 2;
    unsigned short* xn  = (unsigned short*)p; p += (size_t)N0 * F1 * 2;  // 51.2 MB
    unsigned short* agg = (unsigned short*)p; p += (size_t)N1 * F1 * 2;  // 25.6 MB
    // y aliases xn: xn (25.6M elems) dead after agg128; y (N1*F3=12.8M elems) born at gemm12
    unsigned short* y = xn;

    (void)hipMemsetAsync(gcnt, 0, 2048 * 4, stream);

    // kernel A: bucket scatter (both layers) + x->bf16 + weight permutes
    int A1 = (E1 + 8191) / 8192;
    int A2 = (E2 + 8191) / 8192;
    int B3 = N0 * F1 / 8 / 1024;  // exact: 3125
    scatter_build<<<A1 + A2 + B3 + 64, 1024, 0, stream>>>(
        src1, dst1, src2, dst2, x, W1, W2, gcnt,
        bkt_d1, bkt_d2, bkt_s1, bkt_s2,
        (unsigned int*)xn, Bp1, Bp2, E1, E2, A1, A2, B3);

    // kernel B: per-bucket CSR + degree norms
    bucket_build<<<NB1D + NB2D + NB1S + NB2S, 256, 0, stream>>>(
        gcnt, bkt_d1, bkt_d2, bkt_s1, bkt_s2,
        csr1, cnt_in1, rs_in1, csr2, cnt_in2, rs_in2, rs_out1, rs_out2);

    // layer 1 aggregation (per-edge src norm)
    agg128_kernel<<<(N1 + 3) / 4, 256, 0, stream>>>((const unsigned int*)xn, csr1,
                                                    cnt_in1, rs_out1,
                                                    (unsigned int*)agg, N1);

    // fused: hn = relu(rs_in1*(agg@W1)+b1)*rs_out2 ; y = hn@W2
    gemm12<<<(N1 + 127) / 128, 512, 0, stream>>>(agg, Bp1, Bp2, rs_in1, rs_out2, b1, y, N1);

    // layer 2 aggregation + fused epilogue: out = relu(rs_in2*segsum(y) + b2)
    agg_final<<<(N2 + 3) / 4, 256, 0, stream>>>((const unsigned int*)y, csr2, cnt_in2,
                                                rs_in2, b2, (float*)d_out, N2);
}

// Round 6
// 349.344 us; speedup vs baseline: 1.2649x; 1.0391x over previous
//
#include <hip/hip_runtime.h>
#include <hip/hip_bf16.h>

#define F1 128
#define F2 256
#define F3 128
#define CAP 64

// bucket geometry: 256 nodes per bucket
#define NB1D 391   // ceil(100000/256) dst1 buckets
#define NB2D 196   // ceil(50000/256)  dst2 buckets
#define NB1S 782   // ceil(200000/256) src1 buckets
#define NB2S 391   // ceil(100000/256) src2 buckets
#define CAPD 4608  // dst-bucket capacity (mean ~4092, sd ~64 -> 8 sigma)
#define CAPS 2432  // src-bucket capacity (mean ~2046, sd ~45 -> 8.5 sigma)
// gcnt layout offsets
#define GD1 0
#define GD2 391
#define GS1 587
#define GS2 1369

#define YPAD 100096  // gemm12 writes zero rows [N1, YPAD); row N1 = agg_final sentinel

typedef __attribute__((ext_vector_type(8))) short bf16x8;
typedef __attribute__((ext_vector_type(4))) float f32x4;
typedef __attribute__((ext_vector_type(4))) unsigned int u32x4;

__device__ inline float bf2f(unsigned short u) {
    return __uint_as_float(((unsigned int)u) << 16);
}
__device__ inline unsigned short f2bf(float f) {
    __hip_bfloat16 b = __float2bfloat16(f);
    return *reinterpret_cast<unsigned short*>(&b);
}
__device__ inline unsigned int pack2(float lo, float hi) {
    return ((unsigned int)f2bf(hi) << 16) | f2bf(lo);
}

// accumulate one gathered row (u) scaled by c into acc[0..7]
#define ACC_ROW(u, c)                                   \
    acc[0] = fmaf(c, bf2f(u.x & 0xffff), acc[0]);       \
    acc[1] = fmaf(c, bf2f(u.x >> 16), acc[1]);          \
    acc[2] = fmaf(c, bf2f(u.y & 0xffff), acc[2]);       \
    acc[3] = fmaf(c, bf2f(u.y >> 16), acc[3]);          \
    acc[4] = fmaf(c, bf2f(u.z & 0xffff), acc[4]);       \
    acc[5] = fmaf(c, bf2f(u.z >> 16), acc[5]);          \
    acc[6] = fmaf(c, bf2f(u.w & 0xffff), acc[6]);       \
    acc[7] = fmaf(c, bf2f(u.w >> 16), acc[7]);

// unconditional accumulate (sentinel-row masking)
#define ACC_ROW_ADD(u)                          \
    acc[0] += bf2f(u.x & 0xffff);               \
    acc[1] += bf2f(u.x >> 16);                  \
    acc[2] += bf2f(u.y & 0xffff);               \
    acc[3] += bf2f(u.y >> 16);                  \
    acc[4] += bf2f(u.z & 0xffff);               \
    acc[5] += bf2f(u.z >> 16);                  \
    acc[6] += bf2f(u.w & 0xffff);               \
    acc[7] += bf2f(u.w >> 16);

// ---------------------------------------------------------------- kernel A (1024 thr)
// block ranges: [0,A1) L1 edge scatter (8192 edges), [A1,A1+A2) L2,
// [+B3) x fp32->bf16 (8192 elems/block), [+64) weight permutes (32 blocks each).
// Edge blocks use LDS-staged bucket-sorted flush: scattered 4B/1B cursor writes
// (round-0: WRITE 135 MB vs 63 useful, L2 line RMW thrash) are replaced by
// wave-coalesced run writes (consecutive lanes -> consecutive addresses).
__global__ __launch_bounds__(1024) void scatter_build(
    const int* __restrict__ src1, const int* __restrict__ dst1,
    const int* __restrict__ src2, const int* __restrict__ dst2,
    const float* __restrict__ x, const float* __restrict__ W1,
    const float* __restrict__ W2, int* __restrict__ gcnt,
    unsigned int* __restrict__ bkt_d1, unsigned int* __restrict__ bkt_d2,
    unsigned char* __restrict__ bkt_s1, unsigned char* __restrict__ bkt_s2,
    unsigned int* __restrict__ xn, unsigned short* __restrict__ Bp1,
    unsigned short* __restrict__ Bp2, int E1, int E2, int A1, int A2, int B3) {
    __shared__ int hist[800];            // counts (max NBs = 782)
    __shared__ int scanA[800], scanB[800];
    __shared__ unsigned int stg[8192];   // bucket-sorted staged entries
    __shared__ unsigned short bmap[8192];// stage index -> bucket id
    int b = blockIdx.x, t = threadIdx.x;

    if (b < A1 + A2) {
        const int L1 = (b < A1);
        const int* __restrict__ src = L1 ? src1 : src2;
        const int* __restrict__ dst = L1 ? dst1 : dst2;
        const int E = L1 ? E1 : E2;
        const int NBd = L1 ? NB1D : NB2D;
        const int NBs = L1 ? NB1S : NB2S;
        int* gd = gcnt + (L1 ? GD1 : GD2);
        int* gs = gcnt + (L1 ? GS1 : GS2);
        unsigned int* bd = L1 ? bkt_d1 : bkt_d2;
        unsigned char* bs = L1 ? bkt_s1 : bkt_s2;
        int e0 = (L1 ? b : b - A1) * 8192;
        // load edges to registers once
        int se[8], de[8];
#pragma unroll
        for (int k = 0; k < 8; ++k) {
            int e = e0 + k * 1024 + t;
            se[k] = -1;
            de[k] = -1;
            if (e < E) {
                se[k] = src[e];
                de[k] = dst[e];
            }
        }

        // ================= phase A: dst buckets (value = s<<8 | d&255) ==
        for (int i = t; i < NBd; i += 1024) hist[i] = 0;
        __syncthreads();
#pragma unroll
        for (int k = 0; k < 8; ++k)
            if (de[k] >= 0) atomicAdd(&hist[de[k] >> 8], 1);
        __syncthreads();
        // inclusive scan (Hillis-Steele ping-pong)
        {
            int* sa = scanA;
            int* sb = scanB;
            for (int i = t; i < NBd; i += 1024) sa[i] = hist[i];
            __syncthreads();
            for (int off = 1; off < NBd; off <<= 1) {
                for (int i = t; i < NBd; i += 1024) {
                    int v = sa[i];
                    if (i >= off) v += sa[i - off];
                    sb[i] = v;
                }
                __syncthreads();
                int* tp = sa; sa = sb; sb = tp;
            }
            // sa = inclusive scan; sb = scratch -> stage cursors (excl starts)
            for (int i = t; i < NBd; i += 1024) sb[i] = sa[i] - hist[i];
            __syncthreads();
#pragma unroll
            for (int k = 0; k < 8; ++k) {
                if (de[k] >= 0) {
                    int bk = de[k] >> 8;
                    int p = atomicAdd(&sb[bk], 1);
                    stg[p] = ((unsigned int)se[k] << 8) | (de[k] & 255);
                    bmap[p] = (unsigned short)bk;
                }
            }
            __syncthreads();
            // reserve global runs; sb[i] := gbase_i - lstart_i
            for (int i = t; i < NBd; i += 1024) {
                int c = hist[i];
                int g = c ? atomicAdd(&gd[i], c) : 0;
                sb[i] = g - (sa[i] - c);
            }
            __syncthreads();
            int total = sa[NBd - 1];
            // coalesced flush: consecutive i -> consecutive addresses per run
            for (int i = t; i < total; i += 1024) {
                int bk = bmap[i];
                int gpos = sb[bk] + i;
                if (gpos < CAPD) bd[(size_t)bk * CAPD + gpos] = stg[i];
            }
        }
        __syncthreads();

        // ================= phase B: src buckets (value = s&255, byte) ====
        for (int i = t; i < NBs; i += 1024) hist[i] = 0;
        __syncthreads();
#pragma unroll
        for (int k = 0; k < 8; ++k)
            if (se[k] >= 0) atomicAdd(&hist[se[k] >> 8], 1);
        __syncthreads();
        {
            int* sa = scanA;
            int* sb = scanB;
            for (int i = t; i < NBs; i += 1024) sa[i] = hist[i];
            __syncthreads();
            for (int off = 1; off < NBs; off <<= 1) {
                for (int i = t; i < NBs; i += 1024) {
                    int v = sa[i];
                    if (i >= off) v += sa[i - off];
                    sb[i] = v;
                }
                __syncthreads();
                int* tp = sa; sa = sb; sb = tp;
            }
            for (int i = t; i < NBs; i += 1024) sb[i] = sa[i] - hist[i];
            __syncthreads();
#pragma unroll
            for (int k = 0; k < 8; ++k) {
                if (se[k] >= 0) {
                    int bk = se[k] >> 8;
                    int p = atomicAdd(&sb[bk], 1);
                    stg[p] = (unsigned int)(se[k] & 255);
                    bmap[p] = (unsigned short)bk;
                }
            }
            __syncthreads();
            for (int i = t; i < NBs; i += 1024) {
                int c = hist[i];
                int g = c ? atomicAdd(&gs[i], c) : 0;
                sb[i] = g - (sa[i] - c);
            }
            __syncthreads();
            int total = sa[NBs - 1];
            for (int i = t; i < total; i += 1024) {
                int bk = bmap[i];
                int gpos = sb[bk] + i;
                if (gpos < CAPS) bs[(size_t)bk * CAPS + gpos] = (unsigned char)stg[i];
            }
        }
    } else if (b < A1 + A2 + B3) {
        // x fp32 -> bf16, 8 elems/thread, exact thread count. NT loads keep
        // the read-once x stream out of L2.
        size_t tid = (size_t)(b - A1 - A2) * 1024 + t;
        const f32x4* xp = (const f32x4*)x;
        f32x4 a = __builtin_nontemporal_load(xp + tid * 2);
        f32x4 c = __builtin_nontemporal_load(xp + tid * 2 + 1);
        u32x4 o;
        o.x = pack2(a.x, a.y);
        o.y = pack2(a.z, a.w);
        o.z = pack2(c.x, c.y);
        o.w = pack2(c.z, c.w);
        ((u32x4*)xn)[tid] = o;
    } else {
        int w = b - (A1 + A2 + B3);          // 0..63; 32 blocks per weight
        int which = w >> 5;
        const float* W = which ? W2 : W1;
        unsigned short* out = which ? Bp2 : Bp1;
        int N = which ? F3 : F2;
        int idx = (w & 31) * 1024 + t;       // both weights have 32768 elems
        int k = idx / N, n = idx % N;
        unsigned short v = f2bf(W[idx]);
        int kt = k >> 5, q = (k >> 3) & 3, j = k & 7;
        int nt = n >> 4, lane = q * 16 + (n & 15);
        int NT = N >> 4;
        out[(((kt * NT + nt) * 64 + lane) << 3) + j] = v;
    }
}

// ---------------------------------------------------------------- kernel B (512 thr)
// one block per bucket. dst-buckets: padded CSR + cnt_in + rs_in.
// src-buckets: degree histogram -> rs_out.
__global__ __launch_bounds__(512) void bucket_build(
    const int* __restrict__ gcnt,
    const unsigned int* __restrict__ bkt_d1, const unsigned int* __restrict__ bkt_d2,
    const unsigned char* __restrict__ bkt_s1, const unsigned char* __restrict__ bkt_s2,
    int* __restrict__ csr1, int* __restrict__ cnt_in1, float* __restrict__ rs_in1,
    int* __restrict__ csr2, int* __restrict__ cnt_in2, float* __restrict__ rs_in2,
    float* __restrict__ rs_out1, float* __restrict__ rs_out2) {
    __shared__ int hist[256];
    int b = blockIdx.x, t = threadIdx.x;
    if (t < 256) hist[t] = 0;
    __syncthreads();

    if (b < NB1D + NB2D) {
        const int L1 = (b < NB1D);
        int bb = L1 ? b : b - NB1D;
        const unsigned int* bkt = L1 ? bkt_d1 : bkt_d2;
        int* csr = L1 ? csr1 : csr2;
        int* cnt_in = L1 ? cnt_in1 : cnt_in2;
        float* rs_in = L1 ? rs_in1 : rs_in2;
        int Nd = L1 ? 100000 : 50000;
        int n = gcnt[(L1 ? GD1 : GD2) + bb];
        if (n > CAPD) n = CAPD;
        size_t base = (size_t)bb * CAPD;
        for (int i = t; i < n; i += 512) {
            unsigned int v = bkt[base + i];
            int d = v & 255, s = (int)(v >> 8);
            int pos = atomicAdd(&hist[d], 1);
            if (pos < CAP) csr[((size_t)(bb * 256 + d)) * CAP + pos] = s;
        }
        __syncthreads();
        int node = bb * 256 + t;
        if (t < 256 && node < Nd) {
            int c = hist[t];
            cnt_in[node] = c < CAP ? c : CAP;
            rs_in[node] = rsqrtf((float)(c < 1 ? 1 : c));
        }
    } else {
        const int L1 = (b < NB1D + NB2D + NB1S);
        int bb = L1 ? b - (NB1D + NB2D) : b - (NB1D + NB2D + NB1S);
        const unsigned char* bkt = L1 ? bkt_s1 : bkt_s2;
        float* rs_out = L1 ? rs_out1 : rs_out2;
        int Ns = L1 ? 200000 : 100000;
        int n = gcnt[(L1 ? GS1 : GS2) + bb];
        if (n > CAPS) n = CAPS;
        size_t base = (size_t)bb * CAPS;
        for (int i = t; i < n; i += 512) atomicAdd(&hist[bkt[base + i]], 1);
        __syncthreads();
        int node = bb * 256 + t;
        if (t < 256 && node < Ns) rs_out[node] = rsqrtf((float)(hist[t] < 1 ? 1 : hist[t]));
    }
}

// ---------------------------------------------------------------- gather aggregation
// F=128 bf16 rows, one wave per dst row. eg = lane>>4 picks one of 4 edges per
// group, fs = lane&15 picks a 16B feature slot. 16 edges/iteration = 4
// independent u32x4 row-gathers. Edge ids + norms preloaded once and
// distributed via __shfl. Near random-granule DRAM roofline (~3.6 TB/s).
__global__ __launch_bounds__(256) void agg128_kernel(
    const unsigned int* __restrict__ X, const int* __restrict__ csr,
    const int* __restrict__ cnt, const float* __restrict__ rs_src,
    unsigned int* __restrict__ out, int ndst) {
    int wave = (int)((blockIdx.x * blockDim.x + threadIdx.x) >> 6);
    int lane = threadIdx.x & 63;
    if (wave >= ndst) return;
    size_t base = (size_t)wave * CAP;
    int len = cnt[wave];
    int sl = 0;
    float clv = 0.f;
    if (lane < len) {
        sl = csr[base + lane];
        clv = rs_src[sl];
    }
    int eg = lane >> 4, fs = lane & 15;
    float acc[8];
#pragma unroll
    for (int i = 0; i < 8; ++i) acc[i] = 0.f;
    for (int j = 0; j < len; j += 16) {
        int jA = j + eg, jB = j + 4 + eg, jC = j + 8 + eg, jD = j + 12 + eg;
        int sA = __shfl(sl, jA);
        int sB = __shfl(sl, jB);
        int sC = __shfl(sl, jC);
        int sD = __shfl(sl, jD);
        float cA = __shfl(clv, jA);
        float cB = __shfl(clv, jB);
        float cC = __shfl(clv, jC);
        float cD = __shfl(clv, jD);
        u32x4 uA = *(const u32x4*)(X + (size_t)sA * 64 + (fs << 2));
        u32x4 uB = *(const u32x4*)(X + (size_t)sB * 64 + (fs << 2));
        u32x4 uC = *(const u32x4*)(X + (size_t)sC * 64 + (fs << 2));
        u32x4 uD = *(const u32x4*)(X + (size_t)sD * 64 + (fs << 2));
        ACC_ROW(uA, cA)
        ACC_ROW(uB, cB)
        ACC_ROW(uC, cC)
        ACC_ROW(uD, cD)
    }
#pragma unroll
    for (int i = 0; i < 8; ++i) {
        acc[i] += __shfl_xor(acc[i], 16);
        acc[i] += __shfl_xor(acc[i], 32);
    }
    if (eg == 0) {
        u32x4 o;
        o.x = pack2(acc[0], acc[1]);
        o.y = pack2(acc[2], acc[3]);
        o.z = pack2(acc[4], acc[5]);
        o.w = pack2(acc[6], acc[7]);
        *((u32x4*)(out + (size_t)wave * 64) + fs) = o;
    }
}

// ---------------------------------------------------------------- fused two-stage GEMM
// 512 threads = 8 waves x 16 rows = 128-row tile. B matrices staged in LDS.
// Pad rows [M, YPAD) are written as ZEROS (agg_final sentinel rows).
__global__ __launch_bounds__(512) void gemm12(
    const unsigned short* __restrict__ A,    // agg [M,128] bf16
    const unsigned short* __restrict__ Bp1,  // W1 fragments (K=128,N=256)
    const unsigned short* __restrict__ Bp2,  // W2 fragments (K=256,N=128)
    const float* __restrict__ rs1, const float* __restrict__ rs2,
    const float* __restrict__ bias1,
    unsigned short* __restrict__ Y, int M) {
    __shared__ unsigned short Bs[32768];      // 64 KB, holds Bp1 then Bp2
    __shared__ unsigned short tmp[128][264];  // +8 pad, 67.6 KB
    int lane = threadIdx.x & 63, wid = threadIdx.x >> 6;
    int t = threadIdx.x;
    int row0 = blockIdx.x * 128 + wid * 16;
    int q = lane >> 4, col = lane & 15;

    // ---- phase 0: Bp1 -> LDS (4096 uint4 / 512 threads = 8 iters)
#pragma unroll
    for (int i = 0; i < 8; ++i)
        ((u32x4*)Bs)[i * 512 + t] = ((const u32x4*)Bp1)[i * 512 + t];
    __syncthreads();

    // ---- stage 1: 16 rows x 256 cols per wave
    int mload = row0 + col;
    if (mload > M - 1) mload = M - 1;
    const unsigned short* Arow = A + (size_t)mload * F1 + q * 8;
    f32x4 acc[16];
#pragma unroll
    for (int i = 0; i < 16; ++i) acc[i] = (f32x4){0.f, 0.f, 0.f, 0.f};
#pragma unroll
    for (int kt = 0; kt < 4; ++kt) {
        bf16x8 a = *(const bf16x8*)(Arow + kt * 32);
#pragma unroll
        for (int nt = 0; nt < 16; ++nt) {
            bf16x8 bfr = *(const bf16x8*)(Bs + (((kt * 16 + nt) * 64 + lane) << 3));
            acc[nt] = __builtin_amdgcn_mfma_f32_16x16x32_bf16(a, bfr, acc[nt], 0, 0, 0);
        }
    }
#pragma unroll
    for (int r = 0; r < 4; ++r) {
        int lrow = wid * 16 + q * 4 + r;
        int m = row0 + q * 4 + r;
        int mc = m < M ? m : M - 1;
        float s1 = rs1[mc], s2 = rs2[mc];
#pragma unroll
        for (int nt = 0; nt < 16; ++nt) {
            float v = fmaxf(fmaf(acc[nt][r], s1, bias1[nt * 16 + col]), 0.f) * s2;
            tmp[lrow][nt * 16 + col] = f2bf(v);
        }
    }
    __syncthreads();

    // ---- phase 2: Bp2 -> LDS (overwrite Bp1 region)
#pragma unroll
    for (int i = 0; i < 8; ++i)
        ((u32x4*)Bs)[i * 512 + t] = ((const u32x4*)Bp2)[i * 512 + t];
    __syncthreads();

    // ---- stage 2: same 16 rows x 128 cols, K=256 from tmp
    f32x4 acc2[8];
#pragma unroll
    for (int i = 0; i < 8; ++i) acc2[i] = (f32x4){0.f, 0.f, 0.f, 0.f};
    const unsigned short* trow = &tmp[wid * 16 + col][q * 8];
#pragma unroll
    for (int kt = 0; kt < 8; ++kt) {
        bf16x8 a = *(const bf16x8*)(trow + kt * 32);
#pragma unroll
        for (int nt = 0; nt < 8; ++nt) {
            bf16x8 bfr = *(const bf16x8*)(Bs + (((kt * 8 + nt) * 64 + lane) << 3));
            acc2[nt] = __builtin_amdgcn_mfma_f32_16x16x32_bf16(a, bfr, acc2[nt], 0, 0, 0);
        }
    }
#pragma unroll
    for (int r = 0; r < 4; ++r) {
        int m = row0 + q * 4 + r;
        int live = m < M;
#pragma unroll
        for (int nt = 0; nt < 8; ++nt)
            Y[(size_t)m * F3 + nt * 16 + col] = live ? f2bf(acc2[nt][r]) : (unsigned short)0;
    }
}

// ---------------------------------------------------------------- final aggregation
// gather y rows (128 bf16), sum, out = relu(rs_in2[d]*sum + b2) -> fp32
// Dead lanes point at the zero sentinel row (zrow) -> unconditional adds,
// no mask shuffles.
__global__ __launch_bounds__(256) void agg_final(
    const unsigned int* __restrict__ Yv, const int* __restrict__ csr,
    const int* __restrict__ cnt, const float* __restrict__ rs_dst,
    const float* __restrict__ b2, float* __restrict__ out, int ndst, int zrow) {
    int wave = (int)((blockIdx.x * blockDim.x + threadIdx.x) >> 6);
    int lane = threadIdx.x & 63;
    if (wave >= ndst) return;
    size_t base = (size_t)wave * CAP;
    int len = cnt[wave];
    int sl = zrow;
    if (lane < len) sl = csr[base + lane];
    int eg = lane >> 4, fs = lane & 15;
    float acc[8];
#pragma unroll
    for (int i = 0; i < 8; ++i) acc[i] = 0.f;
    for (int j = 0; j < len; j += 16) {
        int jA = j + eg, jB = j + 4 + eg, jC = j + 8 + eg, jD = j + 12 + eg;
        int sA = __shfl(sl, jA);
        int sB = __shfl(sl, jB);
        int sC = __shfl(sl, jC);
        int sD = __shfl(sl, jD);
        u32x4 uA = *(const u32x4*)(Yv + (size_t)sA * 64 + (fs << 2));
        u32x4 uB = *(const u32x4*)(Yv + (size_t)sB * 64 + (fs << 2));
        u32x4 uC = *(const u32x4*)(Yv + (size_t)sC * 64 + (fs << 2));
        u32x4 uD = *(const u32x4*)(Yv + (size_t)sD * 64 + (fs << 2));
        ACC_ROW_ADD(uA)
        ACC_ROW_ADD(uB)
        ACC_ROW_ADD(uC)
        ACC_ROW_ADD(uD)
    }
#pragma unroll
    for (int i = 0; i < 8; ++i) {
        acc[i] += __shfl_xor(acc[i], 16);
        acc[i] += __shfl_xor(acc[i], 32);
    }
    if (eg < 2) {
        float sc = rs_dst[wave];
        f32x4 bias = ((const f32x4*)b2)[(fs << 1) | eg];
        float v0 = eg ? acc[4] : acc[0];
        float v1 = eg ? acc[5] : acc[1];
        float v2 = eg ? acc[6] : acc[2];
        float v3 = eg ? acc[7] : acc[3];
        f32x4 o;
        o.x = fmaxf(fmaf(v0, sc, bias.x), 0.f);
        o.y = fmaxf(fmaf(v1, sc, bias.y), 0.f);
        o.z = fmaxf(fmaf(v2, sc, bias.z), 0.f);
        o.w = fmaxf(fmaf(v3, sc, bias.w), 0.f);
        __builtin_nontemporal_store(o, (f32x4*)out + (size_t)wave * 32 + (fs << 1) + eg);
    }
}

extern "C" void kernel_launch(void* const* d_in, const int* in_sizes, int n_in,
                              void* d_out, int out_size, void* d_ws, size_t ws_size,
                              hipStream_t stream) {
    const float* x  = (const float*)d_in[0];
    const float* W1 = (const float*)d_in[1];
    const float* b1 = (const float*)d_in[2];
    const float* W2 = (const float*)d_in[3];
    const float* b2 = (const float*)d_in[4];
    const int* src1 = (const int*)d_in[5];
    const int* dst1 = (const int*)d_in[6];
    const int* src2 = (const int*)d_in[7];
    const int* dst2 = (const int*)d_in[8];
    const int E1 = in_sizes[5], E2 = in_sizes[7];
    const int N0 = in_sizes[0] / F1;  // 200000
    const int N1 = 100000, N2 = 50000;

    // ---- workspace layout (all segment sizes multiples of 16 B)
    char* p = (char*)d_ws;
    int* gcnt = (int*)p; p += 2048 * 4;                          // 1760 used
    float* rs_out1 = (float*)p; p += (size_t)N0 * 4;
    float* rs_in1  = (float*)p; p += (size_t)N1 * 4;
    float* rs_out2 = (float*)p; p += (size_t)N1 * 4;
    float* rs_in2  = (float*)p; p += (size_t)N2 * 4;
    int* cnt_in1 = (int*)p; p += (size_t)N1 * 4;
    int* cnt_in2 = (int*)p; p += (size_t)N2 * 4;
    unsigned int* bkt_d1 = (unsigned int*)p; p += (size_t)NB1D * CAPD * 4;  // 7.2 MB
    unsigned int* bkt_d2 = (unsigned int*)p; p += (size_t)NB2D * CAPD * 4;  // 3.6 MB
    unsigned char* bkt_s1 = (unsigned char*)p; p += (size_t)NB1S * CAPS;    // 1.9 MB
    unsigned char* bkt_s2 = (unsigned char*)p; p += (size_t)NB2S * CAPS;    // 1.0 MB
    int* csr1 = (int*)p; p += (size_t)N1 * CAP * 4;              // 25.6 MB
    int* csr2 = (int*)p; p += (size_t)N2 * CAP * 4;              // 12.8 MB
    unsigned short* Bp1 = (unsigned short*)p; p += (size_t)F1 * F2 * 2;
    unsigned short* Bp2 = (unsigned short*)p; p += (size_t)F2 * F3 * 2;
    unsigned short* xn  = (unsigned short*)p; p += (size_t)N0 * F1 * 2;  // 51.2 MB
    unsigned short* agg = (unsigned short*)p; p += (size_t)N1 * F1 * 2;  // 25.6 MB
    // y aliases xn: xn (25.6M elems) dead after agg128; y (YPAD*F3=12.81M elems)
    // born at gemm12 (incl. zero pad rows [N1, YPAD) used as agg_final sentinel)
    unsigned short* y = xn;

    (void)hipMemsetAsync(gcnt, 0, 2048 * 4, stream);

    // kernel A: bucket scatter (both layers) + x->bf16 + weight permutes
    int A1 = (E1 + 8191) / 8192;
    int A2 = (E2 + 8191) / 8192;
    int B3 = N0 * F1 / 8 / 1024;  // exact: 3125
    scatter_build<<<A1 + A2 + B3 + 64, 1024, 0, stream>>>(
        src1, dst1, src2, dst2, x, W1, W2, gcnt,
        bkt_d1, bkt_d2, bkt_s1, bkt_s2,
        (unsigned int*)xn, Bp1, Bp2, E1, E2, A1, A2, B3);

    // kernel B: per-bucket CSR + degree norms
    bucket_build<<<NB1D + NB2D + NB1S + NB2S, 512, 0, stream>>>(
        gcnt, bkt_d1, bkt_d2, bkt_s1, bkt_s2,
        csr1, cnt_in1, rs_in1, csr2, cnt_in2, rs_in2, rs_out1, rs_out2);

    // layer 1 aggregation (per-edge src norm)
    agg128_kernel<<<(N1 + 3) / 4, 256, 0, stream>>>((const unsigned int*)xn, csr1,
                                                    cnt_in1, rs_out1,
                                                    (unsigned int*)agg, N1);

    // fused: hn = relu(rs_in1*(agg@W1)+b1)*rs_out2 ; y = hn@W2  (+ zero pad rows)
    gemm12<<<(N1 + 127) / 128, 512, 0, stream>>>(agg, Bp1, Bp2, rs_in1, rs_out2, b1, y, N1);

    // layer 2 aggregation + fused epilogue: out = relu(rs_in2*segsum(y) + b2)
    agg_final<<<(N2 + 3) / 4, 256, 0, stream>>>((const unsigned int*)y, csr2, cnt_in2,
                                                rs_in2, b2, (float*)d_out, N2, N1);
}